// Round 1
// baseline (1722.777 us; speedup 1.0000x reference)
//
#include <hip/hip_runtime.h>

// ---- problem constants ----
#define BATCH 8
#define CIN   512
#define NH    8
#define DH    128
#define PP    1024   // 32*32 positions
#define QK_SCALE 0.08838834764831845f  // 128^-0.5

// workspace layout (floats):
//   Q  [BATCH*NH][PP][DH]  (pre-scaled by QK_SCALE)
//   K  [BATCH*NH][PP][DH]
//   V  [BATCH*NH][PP][DH]
//   R  [BATCH*NH][PP][64]  (j<32: q.rel_height[j-h+31]; j>=32: q.rel_width[(j-32)-w+31])
#define QKV_ELEMS (BATCH * NH * PP * DH)   // 8388608

// ============================================================================
// Kernel 1: QKV projection.  qkv[b][o][p] = sum_c w[o][c] * fm[b][c][p]
// Computed as C'[p][o] tiles (128x128, Ktile=16, 256 thr, 8x8/thread) and
// scattered directly into Q/K/V row-major [bn][p][dd] (Q scaled).
// ============================================================================
__global__ __launch_bounds__(256) void qkv_kernel(
    const float* __restrict__ fm, const float* __restrict__ w,
    float* __restrict__ Qo, float* __restrict__ Ko, float* __restrict__ Vo)
{
    __shared__ float As[16][128];   // fm[c-tile][p-tile]
    __shared__ float Bs[16][128];   // w [c-tile][o-tile]

    const int t  = threadIdx.x;
    const int b  = blockIdx.z;
    const int p0 = blockIdx.x * 128;
    const int o0 = blockIdx.y * 128;
    const int ty = t >> 4, tx = t & 15;

    float acc[8][8];
#pragma unroll
    for (int i = 0; i < 8; ++i)
#pragma unroll
        for (int j = 0; j < 8; ++j) acc[i][j] = 0.f;

    const float* fmb = fm + (size_t)b * CIN * PP;

    for (int c0 = 0; c0 < CIN; c0 += 16) {
        __syncthreads();
        // As[cc][pp]: 512 float4, 2 per thread, coalesced along p
#pragma unroll
        for (int ii = 0; ii < 2; ++ii) {
            int f  = t + 256 * ii;
            int cc = f >> 5, pp = f & 31;
            float4 v = *(const float4*)(fmb + (size_t)(c0 + cc) * PP + p0 + pp * 4);
            *(float4*)(&As[cc][pp * 4]) = v;
        }
        // Bs[cc][o] = w[(o0+o)][c0+cc]  (transpose on load)
        {
            int o = t >> 1, ch = (t & 1) * 8;
            const float* wrow = w + (size_t)(o0 + o) * CIN + c0 + ch;
            float4 v0 = *(const float4*)(wrow);
            float4 v1 = *(const float4*)(wrow + 4);
            Bs[ch + 0][o] = v0.x; Bs[ch + 1][o] = v0.y;
            Bs[ch + 2][o] = v0.z; Bs[ch + 3][o] = v0.w;
            Bs[ch + 4][o] = v1.x; Bs[ch + 5][o] = v1.y;
            Bs[ch + 6][o] = v1.z; Bs[ch + 7][o] = v1.w;
        }
        __syncthreads();
#pragma unroll
        for (int cc = 0; cc < 16; ++cc) {
            float a[8], bb[8];
            float4 a0 = *(const float4*)(&As[cc][ty * 8]);
            float4 a1 = *(const float4*)(&As[cc][ty * 8 + 4]);
            a[0] = a0.x; a[1] = a0.y; a[2] = a0.z; a[3] = a0.w;
            a[4] = a1.x; a[5] = a1.y; a[6] = a1.z; a[7] = a1.w;
#pragma unroll
            for (int j = 0; j < 8; ++j) bb[j] = Bs[cc][tx + 16 * j];  // stride-16: conflict-free
#pragma unroll
            for (int i = 0; i < 8; ++i)
#pragma unroll
                for (int j = 0; j < 8; ++j) acc[i][j] += a[i] * bb[j];
        }
    }

    // scatter: o-tile (128 wide, 128-aligned) falls entirely in one (t,n) slice
    const int tsel = o0 >> 10;             // 0=Q 1=K 2=V
    const int n    = (o0 >> 7) & 7;
    float* outb = (tsel == 0) ? Qo : ((tsel == 1) ? Ko : Vo);
    const float scl = (tsel == 0) ? QK_SCALE : 1.0f;
    const int bn = b * NH + n;
#pragma unroll
    for (int i = 0; i < 8; ++i) {
        const int p = p0 + ty * 8 + i;
        float* row = outb + ((size_t)bn * PP + p) * DH;
#pragma unroll
        for (int j = 0; j < 8; ++j) {
            row[tx + 16 * j] = acc[i][j] * scl;
        }
    }
}

// ============================================================================
// Kernel 2: relative-position dots.
// R[bn][p][j] = dot(Q[bn][p], j<32 ? rel_h[j - h + 31] : rel_w[(j-32) - w + 31])
// ============================================================================
__global__ __launch_bounds__(256) void rel_kernel(
    const float* __restrict__ Q,
    const float* __restrict__ relH, const float* __restrict__ relW,
    float* __restrict__ R)
{
    __shared__ float Qs[4][128];
    const int t     = threadIdx.x;
    const int blk   = blockIdx.x;        // 64 * 256 blocks
    const int bn    = blk >> 8;
    const int pbase = (blk & 255) * 4;

    if (t < 128) {
        ((float4*)(&Qs[0][0]))[t] =
            ((const float4*)(Q + ((size_t)bn * PP + pbase) * DH))[t];
    }
    __syncthreads();

    const int lp = t >> 6, j = t & 63;
    const int p = pbase + lp;
    const int h = p >> 5, wq = p & 31;
    const float* rel = (j < 32) ? (relH + (size_t)(j - h + 31) * DH)
                                : (relW + (size_t)((j - 32) - wq + 31) * DH);
    const float4* q4 = (const float4*)(&Qs[lp][0]);
    const float4* r4 = (const float4*)rel;
    float s = 0.f;
#pragma unroll
    for (int d = 0; d < 32; ++d) {
        float4 a = q4[d], bv = r4[d];
        s += a.x * bv.x + a.y * bv.y + a.z * bv.z + a.w * bv.w;
    }
    R[((size_t)bn * PP + p) * 64 + j] = s;
}

// ============================================================================
// Kernel 3: flash-style attention, one block per (bn, 32-query tile).
// Key tiles of 32 (H = kt constant per tile). Online softmax.
// Q/K tiles XOR-swizzled in LDS (16B slot ^ (row&7)) -> <=2-way reads.
// ============================================================================
__global__ __launch_bounds__(256) void attn_kernel(
    const float* __restrict__ Q, const float* __restrict__ K,
    const float* __restrict__ V, const float* __restrict__ R,
    float* __restrict__ out)
{
    __shared__ float Qs[32 * 128];
    __shared__ float Ks[32 * 128];
    __shared__ float Vs[32 * 128];
    __shared__ float Rs[32][64];
    __shared__ float Ps[32][33];     // +1 pad: row-strided reads conflict-free

    const int t  = threadIdx.x;
    const int bn = blockIdx.y;
    const int q0 = blockIdx.x * 32;
    const int ty = t >> 4, tx = t & 15;
    const int b  = bn >> 3, n = bn & 7;

    // stage Q (swizzled) + R rows
    const float4* Qg = (const float4*)(Q + ((size_t)bn * PP + q0) * DH);
#pragma unroll
    for (int ii = 0; ii < 4; ++ii) {
        int f = t + 256 * ii;            // 1024 float4
        int r = f >> 5, s = f & 31;
        ((float4*)Qs)[r * 32 + (s ^ (r & 7))] = Qg[f];
    }
    const float4* Rg = (const float4*)(R + ((size_t)bn * PP + q0) * 64);
#pragma unroll
    for (int ii = 0; ii < 2; ++ii) {
        int f = t + 256 * ii;            // 512 float4
        ((float4*)(&Rs[0][0]))[f] = Rg[f];
    }

    float m[2] = { -1e30f, -1e30f };
    float l[2] = { 0.f, 0.f };
    float acc[2][8];
#pragma unroll
    for (int i = 0; i < 2; ++i)
#pragma unroll
        for (int j = 0; j < 8; ++j) acc[i][j] = 0.f;

    const float4* Kg = (const float4*)(K + (size_t)bn * PP * DH);
    const float4* Vg = (const float4*)(V + (size_t)bn * PP * DH);

    const int rA = ty, rB = ty + 16, cA = tx, cB = tx + 16;

    for (int kt = 0; kt < 32; ++kt) {
        __syncthreads();
        // stage K (swizzled) and V (linear): 1024 float4 each
#pragma unroll
        for (int ii = 0; ii < 4; ++ii) {
            int f = t + 256 * ii;
            int r = f >> 5, s = f & 31;
            ((float4*)Ks)[r * 32 + (s ^ (r & 7))] = Kg[kt * 1024 + f];
            ((float4*)Vs)[f]                      = Vg[kt * 1024 + f];
        }
        __syncthreads();

        // S[r][c] = Q[r] . K[c]
        float s00 = 0.f, s01 = 0.f, s10 = 0.f, s11 = 0.f;
#pragma unroll
        for (int s = 0; s < 32; ++s) {
            float4 qa = ((const float4*)Qs)[rA * 32 + (s ^ (rA & 7))];
            float4 qb = ((const float4*)Qs)[rB * 32 + (s ^ (rB & 7))];
            float4 ka = ((const float4*)Ks)[cA * 32 + (s ^ (cA & 7))];
            float4 kb = ((const float4*)Ks)[cB * 32 + (s ^ (cB & 7))];
            s00 += qa.x * ka.x + qa.y * ka.y + qa.z * ka.z + qa.w * ka.w;
            s01 += qa.x * kb.x + qa.y * kb.y + qa.z * kb.z + qa.w * kb.w;
            s10 += qb.x * ka.x + qb.y * ka.y + qb.z * ka.z + qb.w * ka.w;
            s11 += qb.x * kb.x + qb.y * kb.y + qb.z * kb.z + qb.w * kb.w;
        }
        // rel terms: key y = kt*32 + c  =>  H = kt, W = c
        s00 += Rs[rA][kt] + Rs[rA][32 + cA];
        s01 += Rs[rA][kt] + Rs[rA][32 + cB];
        s10 += Rs[rB][kt] + Rs[rB][32 + cA];
        s11 += Rs[rB][kt] + Rs[rB][32 + cB];

        // online softmax (row spread over 16 tx lanes)
        float mx0 = fmaxf(s00, s01), mx1 = fmaxf(s10, s11);
#pragma unroll
        for (int d = 1; d < 16; d <<= 1) {
            mx0 = fmaxf(mx0, __shfl_xor(mx0, d));
            mx1 = fmaxf(mx1, __shfl_xor(mx1, d));
        }
        const float mn0 = fmaxf(m[0], mx0), mn1 = fmaxf(m[1], mx1);
        const float al0 = __expf(m[0] - mn0), al1 = __expf(m[1] - mn1);
        const float p00 = __expf(s00 - mn0), p01 = __expf(s01 - mn0);
        const float p10 = __expf(s10 - mn1), p11 = __expf(s11 - mn1);
        float sm0 = p00 + p01, sm1 = p10 + p11;
#pragma unroll
        for (int d = 1; d < 16; d <<= 1) {
            sm0 += __shfl_xor(sm0, d);
            sm1 += __shfl_xor(sm1, d);
        }
        l[0] = l[0] * al0 + sm0;
        l[1] = l[1] * al1 + sm1;
        m[0] = mn0; m[1] = mn1;
#pragma unroll
        for (int j = 0; j < 8; ++j) { acc[0][j] *= al0; acc[1][j] *= al1; }
        Ps[rA][cA] = p00; Ps[rA][cB] = p01;
        Ps[rB][cA] = p10; Ps[rB][cB] = p11;
        __syncthreads();

        // O[r][dd] += sum_c P[r][c] * V[c][dd]
#pragma unroll
        for (int c = 0; c < 32; ++c) {
            const float pa = Ps[rA][c], pb = Ps[rB][c];
#pragma unroll
            for (int j = 0; j < 8; ++j) {
                const float v = Vs[c * 128 + tx + 16 * j];
                acc[0][j] += pa * v;
                acc[1][j] += pb * v;
            }
        }
    }

    const float inv0 = 1.f / l[0], inv1 = 1.f / l[1];
    // out[b][n*128+dd][p]
#pragma unroll
    for (int j = 0; j < 8; ++j) {
        const int dd = tx + 16 * j;
        float* base = out + ((size_t)b * 1024 + n * 128 + dd) * PP + q0;
        base[rA] = acc[0][j] * inv0;
        base[rB] = acc[1][j] * inv1;
    }
}

// ============================================================================
extern "C" void kernel_launch(void* const* d_in, const int* in_sizes, int n_in,
                              void* d_out, int out_size, void* d_ws, size_t ws_size,
                              hipStream_t stream)
{
    const float* fm   = (const float*)d_in[0];
    const float* wqkv = (const float*)d_in[1];
    const float* relH = (const float*)d_in[2];
    const float* relW = (const float*)d_in[3];
    float* out = (float*)d_out;

    float* ws = (float*)d_ws;
    float* Q = ws;
    float* K = ws + (size_t)QKV_ELEMS;
    float* V = ws + (size_t)2 * QKV_ELEMS;
    float* R = ws + (size_t)3 * QKV_ELEMS;

    qkv_kernel<<<dim3(8, 24, 8), 256, 0, stream>>>(fm, wqkv, Q, K, V);
    rel_kernel<<<64 * 256, 256, 0, stream>>>(Q, relH, relW, R);
    attn_kernel<<<dim3(32, 64), 256, 0, stream>>>(Q, K, V, R, out);
}

// Round 3
// 714.287 us; speedup vs baseline: 2.4119x; 2.4119x over previous
//
#include <hip/hip_runtime.h>

// ---- problem constants ----
#define BATCH 8
#define CIN   512
#define NH    8
#define DH    128
#define PP    1024   // 32*32 positions
#define QK_SCALE 0.08838834764831845f  // 128^-0.5

typedef unsigned int  u32;
typedef unsigned short u16;
typedef __attribute__((ext_vector_type(8)))  short short8;
typedef __attribute__((ext_vector_type(16))) float f32x16;

typedef __attribute__((address_space(1))) const u32 GU32;
typedef __attribute__((address_space(3))) u32 LU32;

// workspace layout (bytes):
//   Qhi  [64][1024][128] u16   @ 0        (16 MB)
//   Qlo  [64][1024][128] u16   @ 16 MB    (16 MB)
//   KIMG [64*32][16384]  char  @ 32 MB    (32 MB)  per-tile: hi image 8KB, lo 8KB
//   VIMG [64*32][16384]  char  @ 64 MB    (32 MB)  per-tile: hi image 8KB, lo 8KB
//   R    [64][1024][64]  f32   @ 96 MB    (16 MB)

__device__ inline u32 f2bf(float x) {            // fp32 -> bf16 (RNE)
    u32 u = __float_as_uint(x);
    return (u + 0x7fffu + ((u >> 16) & 1u)) >> 16;
}
__device__ inline float bf2f(u32 h) { return __uint_as_float(h << 16); }

__device__ inline void cvt8(const float* v, float scl, uint4& hv, uint4& lv) {
    u32 h[8], l[8];
#pragma unroll
    for (int j = 0; j < 8; ++j) {
        float x = v[j] * scl;
        u32 hb = f2bf(x);
        float hf = bf2f(hb);
        u32 lb = f2bf(x - hf);
        h[j] = hb; l[j] = lb;
    }
    hv = make_uint4(h[0] | (h[1] << 16), h[2] | (h[3] << 16),
                    h[4] | (h[5] << 16), h[6] | (h[7] << 16));
    lv = make_uint4(l[0] | (l[1] << 16), l[2] | (l[3] << 16),
                    l[4] | (l[5] << 16), l[6] | (l[7] << 16));
}

// ============================================================================
// Kernel 1: QKV projection (fp32 math) with bf16 hi/lo split epilogue:
// Q plain [bn][p][d]; K as swizzled 16KB tile images
// [bn][kt][key r][granule (d/8) ^ (r&15)]; V^T images [bn][kt][d][g ^ (d&3)].
// Thread register tile: 8 consecutive p x 8 consecutive o so each thread owns
// whole 16B output granules in both orientations.
// ============================================================================
__global__ __launch_bounds__(256) void qkv_kernel(
    const float* __restrict__ fm, const float* __restrict__ w,
    u16* __restrict__ Qhi, u16* __restrict__ Qlo,
    char* __restrict__ KIMG, char* __restrict__ VIMG)
{
    __shared__ float As[16][128];   // fm[c-tile][p-tile]
    __shared__ float Bs[16][128];   // w [c-tile][o-tile]

    const int t  = threadIdx.x;
    const int b  = blockIdx.z;
    const int p0 = blockIdx.x * 128;
    const int o0 = blockIdx.y * 128;
    const int ty = t >> 4, tx = t & 15;

    float acc[8][8];
#pragma unroll
    for (int i = 0; i < 8; ++i)
#pragma unroll
        for (int j = 0; j < 8; ++j) acc[i][j] = 0.f;

    const float* fmb = fm + (size_t)b * CIN * PP;

    for (int c0 = 0; c0 < CIN; c0 += 16) {
        __syncthreads();
#pragma unroll
        for (int ii = 0; ii < 2; ++ii) {
            int f  = t + 256 * ii;
            int cc = f >> 5, pp = f & 31;
            float4 v = *(const float4*)(fmb + (size_t)(c0 + cc) * PP + p0 + pp * 4);
            *(float4*)(&As[cc][pp * 4]) = v;
        }
        {
            int o = t >> 1, ch = (t & 1) * 8;
            const float* wrow = w + (size_t)(o0 + o) * CIN + c0 + ch;
            float4 v0 = *(const float4*)(wrow);
            float4 v1 = *(const float4*)(wrow + 4);
            Bs[ch + 0][o] = v0.x; Bs[ch + 1][o] = v0.y;
            Bs[ch + 2][o] = v0.z; Bs[ch + 3][o] = v0.w;
            Bs[ch + 4][o] = v1.x; Bs[ch + 5][o] = v1.y;
            Bs[ch + 6][o] = v1.z; Bs[ch + 7][o] = v1.w;
        }
        __syncthreads();
#pragma unroll
        for (int cc = 0; cc < 16; ++cc) {
            float a[8], bb[8];
            float4 a0 = *(const float4*)(&As[cc][ty * 8]);
            float4 a1 = *(const float4*)(&As[cc][ty * 8 + 4]);
            a[0] = a0.x; a[1] = a0.y; a[2] = a0.z; a[3] = a0.w;
            a[4] = a1.x; a[5] = a1.y; a[6] = a1.z; a[7] = a1.w;
            float4 b0 = *(const float4*)(&Bs[cc][tx * 8]);
            float4 b1 = *(const float4*)(&Bs[cc][tx * 8 + 4]);
            bb[0] = b0.x; bb[1] = b0.y; bb[2] = b0.z; bb[3] = b0.w;
            bb[4] = b1.x; bb[5] = b1.y; bb[6] = b1.z; bb[7] = b1.w;
#pragma unroll
            for (int i = 0; i < 8; ++i)
#pragma unroll
                for (int j = 0; j < 8; ++j) acc[i][j] += a[i] * bb[j];
        }
    }

    const int tsel = o0 >> 10;             // 0=Q 1=K 2=V
    const int n    = (o0 >> 7) & 7;
    const int bn   = b * NH + n;

    if (tsel == 0) {
        // Q planes, scaled:   Qhi/Qlo[bn][p][tx*8 .. +7]
#pragma unroll
        for (int i = 0; i < 8; ++i) {
            const int p = p0 + ty * 8 + i;
            uint4 hv, lv;
            cvt8(&acc[i][0], QK_SCALE, hv, lv);
            const size_t off = ((size_t)bn * PP + p) * DH + tx * 8;
            *(uint4*)(Qhi + off) = hv;
            *(uint4*)(Qlo + off) = lv;
        }
    } else if (tsel == 1) {
        // K image: r = p&31, granule index tx stored at slot tx ^ (r&15)
#pragma unroll
        for (int i = 0; i < 8; ++i) {
            const int p = p0 + ty * 8 + i;
            const int r = p & 31, kt = p >> 5;
            uint4 hv, lv;
            cvt8(&acc[i][0], 1.0f, hv, lv);
            char* base = KIMG + (((size_t)bn * 32 + kt) << 14)
                       + r * 256 + ((tx ^ (r & 15)) << 4);
            *(uint4*)(base)        = hv;
            *(uint4*)(base + 8192) = lv;
        }
    } else {
        // V^T image: granule of 8 consecutive keys (= p rows) at fixed d
        const int kt = (p0 + ty * 8) >> 5;
        const int g  = ty & 3;
#pragma unroll
        for (int j = 0; j < 8; ++j) {
            const int d = tx * 8 + j;
            float tmp[8];
#pragma unroll
            for (int i = 0; i < 8; ++i) tmp[i] = acc[i][j];
            uint4 hv, lv;
            cvt8(tmp, 1.0f, hv, lv);
            char* base = VIMG + (((size_t)bn * 32 + kt) << 14)
                       + d * 64 + ((g ^ (d & 3)) << 4);
            *(uint4*)(base)        = hv;
            *(uint4*)(base + 8192) = lv;
        }
    }
}

// ============================================================================
// Kernel 2: relative-position dots (fp32), reading Q from hi/lo planes.
// R[bn][p][j] = q . (j<32 ? relH[j - h + 31] : relW[(j-32) - w + 31])
// ============================================================================
__global__ __launch_bounds__(256) void rel_kernel(
    const u16* __restrict__ Qhi, const u16* __restrict__ Qlo,
    const float* __restrict__ relH, const float* __restrict__ relW,
    float* __restrict__ R)
{
    __shared__ float Qs[4][128];
    const int t     = threadIdx.x;
    const int blk   = blockIdx.x;        // 64 * 256 blocks
    const int bn    = blk >> 8;
    const int pbase = (blk & 255) * 4;

    if (t < 64) {
        const int row = t >> 4, d0 = (t & 15) * 8;
        const size_t qoff = ((size_t)bn * PP + pbase + row) * DH + d0;
        uint4 hv = *(const uint4*)(Qhi + qoff);
        uint4 lv = *(const uint4*)(Qlo + qoff);
        const u32 hw[4] = {hv.x, hv.y, hv.z, hv.w};
        const u32 lw[4] = {lv.x, lv.y, lv.z, lv.w};
#pragma unroll
        for (int w2 = 0; w2 < 4; ++w2) {
            Qs[row][d0 + w2*2]     = bf2f(hw[w2] & 0xffffu) + bf2f(lw[w2] & 0xffffu);
            Qs[row][d0 + w2*2 + 1] = bf2f(hw[w2] >> 16)     + bf2f(lw[w2] >> 16);
        }
    }
    __syncthreads();

    const int lp = t >> 6, j = t & 63;
    const int p = pbase + lp;
    const int h = p >> 5, wq = p & 31;
    const float* rel = (j < 32) ? (relH + (size_t)(j - h + 31) * DH)
                                : (relW + (size_t)((j - 32) - wq + 31) * DH);
    const float4* q4 = (const float4*)(&Qs[lp][0]);
    const float4* r4 = (const float4*)rel;
    float s = 0.f;
#pragma unroll
    for (int d = 0; d < 32; ++d) {
        float4 a = q4[d], bv = r4[d];
        s += a.x * bv.x + a.y * bv.y + a.z * bv.z + a.w * bv.w;
    }
    R[((size_t)bn * PP + p) * 64 + j] = s;
}

// ============================================================================
// Kernel 3: split-bf16 MFMA flash attention.
// Block = 256 thr (4 waves), 128 q rows (32 per wave), key tiles of 32.
// S^T = mfma(K, Q) so each lane owns one q column (lane-local softmax).
// LDS (80 KB exact): Kbuf0 16K | Kbuf1 16K | Vbuf 16K | P 16K | R1 16K
// ============================================================================
__global__ __launch_bounds__(256, 2) void attn_kernel(
    const u16* __restrict__ Qhi, const u16* __restrict__ Qlo,
    const char* __restrict__ KIMG, const char* __restrict__ VIMG,
    const float* __restrict__ R, float* __restrict__ out)
{
    __shared__ char lds[81920];

    const int t    = threadIdx.x;
    const int lane = t & 63, wid = t >> 6;
    const int bn = blockIdx.y, q0 = blockIdx.x * 128;
    const int b  = bn >> 3,  n = bn & 7;
    const int l31 = lane & 31, h5 = lane >> 5;
    const int q_local = wid * 32 + l31;
    const int q = q0 + q_local;

    // ---- Q fragments (B operand), 8 k-steps x (hi,lo) : 64 VGPR
    short8 qh[8], ql[8];
    {
        const u16* qrh = Qhi + ((size_t)bn * PP + q) * DH + h5 * 8;
        const u16* qrl = Qlo + ((size_t)bn * PP + q) * DH + h5 * 8;
#pragma unroll
        for (int kk = 0; kk < 8; ++kk) {
            qh[kk] = *(const short8*)(qrh + kk * 16);
            ql[kk] = *(const short8*)(qrl + kk * 16);
        }
    }
    // ---- R2 (width rel term): matches C-frag row layout exactly
    float R2a[16];
    {
        const float* r2p = R + ((size_t)bn * PP + q) * 64 + 32 + h5 * 4;
#pragma unroll
        for (int m_ = 0; m_ < 4; ++m_) {
            float4 v = *(const float4*)(r2p + m_ * 8);
            R2a[m_*4+0] = v.x; R2a[m_*4+1] = v.y; R2a[m_*4+2] = v.z; R2a[m_*4+3] = v.w;
        }
    }
    // ---- R1 (height rel term) table -> LDS, XOR-swizzled columns
    float* R1p = (float*)(lds + 65536);
    {
#pragma unroll
        for (int r = 0; r < 4; ++r) {
            int idx = t + 256 * r;              // 1024 float4 = 4096 floats
            int row = idx >> 3, c4 = (idx & 7) * 4;
            float4 v = *(const float4*)(R + ((size_t)bn * PP + q0 + row) * 64 + c4);
            R1p[row * 32 + ((c4 + 0) ^ (row & 31))] = v.x;
            R1p[row * 32 + ((c4 + 1) ^ (row & 31))] = v.y;
            R1p[row * 32 + ((c4 + 2) ^ (row & 31))] = v.z;
            R1p[row * 32 + ((c4 + 3) ^ (row & 31))] = v.w;
        }
    }

    // staging helpers: each wave copies its 4KB quarter of a 16KB tile image
    auto issueK = [&](int kt, int par) {
        const char* src = KIMG + (((size_t)bn * 32 + kt) << 14) + wid * 4096 + lane * 16;
        const char* dst = lds + par * 16384 + wid * 4096;
#pragma unroll
        for (int c = 0; c < 4; ++c)
            __builtin_amdgcn_global_load_lds((GU32*)(src + c * 1024),
                                             (LU32*)(dst + c * 1024), 16, 0, 0);
    };
    auto issueV = [&](int kt) {
        const char* src = VIMG + (((size_t)bn * 32 + kt) << 14) + wid * 4096 + lane * 16;
        const char* dst = lds + 32768 + wid * 4096;
#pragma unroll
        for (int c = 0; c < 4; ++c)
            __builtin_amdgcn_global_load_lds((GU32*)(src + c * 1024),
                                             (LU32*)(dst + c * 1024), 16, 0, 0);
    };

    issueK(0, 0);
    asm volatile("s_waitcnt lgkmcnt(0)" ::: "memory");   // R1 table written
    __builtin_amdgcn_s_barrier();                        // R1 visible block-wide
    __builtin_amdgcn_sched_barrier(0);

    f32x16 o_[4];
#pragma unroll
    for (int i = 0; i < 4; ++i)
#pragma unroll
        for (int r = 0; r < 16; ++r) o_[i][r] = 0.f;

    float m_run = -1e30f, l_run = 0.f;
    u32* Pp = (u32*)(lds + 49152 + wid * 4096);

    for (int kt = 0; kt < 32; ++kt) {
        const int par = kt & 1;
        // -- issue V(t) and K(t+1); buffers free per end-of-prev-iter barrier
        issueV(kt);
        issueK((kt + 1) & 31, par ^ 1);
        // -- wait K(t) (oldest 4), leave V(t)+K(t+1) in flight
        asm volatile("s_waitcnt vmcnt(8)" ::: "memory");
        __builtin_amdgcn_sched_barrier(0);
        __builtin_amdgcn_s_barrier();
        __builtin_amdgcn_sched_barrier(0);

        // ---- QK^T (swapped): S^T[key][q], split-bf16 (3 terms)
        f32x16 s;
#pragma unroll
        for (int r = 0; r < 16; ++r) s[r] = 0.f;
        const char* kb = lds + par * 16384;
#pragma unroll
        for (int kk = 0; kk < 8; ++kk) {
            const int g = kk * 2 + h5;
            const int off = l31 * 256 + ((g ^ (l31 & 15)) << 4);
            short8 kh = *(const short8*)(kb + off);
            short8 kl = *(const short8*)(kb + 8192 + off);
            s = __builtin_amdgcn_mfma_f32_32x32x16_bf16(kh, qh[kk], s, 0, 0, 0);
            s = __builtin_amdgcn_mfma_f32_32x32x16_bf16(kh, ql[kk], s, 0, 0, 0);
            s = __builtin_amdgcn_mfma_f32_32x32x16_bf16(kl, qh[kk], s, 0, 0, 0);
        }
        const float r1 = R1p[q_local * 32 + (kt ^ l31)];

        // ---- online softmax (q is lane-local)
        float mx = -1e30f;
#pragma unroll
        for (int r = 0; r < 16; ++r) {
            s[r] += R2a[r];
            mx = fmaxf(mx, s[r]);
        }
        mx = fmaxf(mx, __shfl_xor(mx, 32));
        const float pmax  = mx + r1;
        const float m_new = fmaxf(m_run, pmax);
        const float alpha = __expf(m_run - m_new);
        const float tsh   = r1 - m_new;
        float rsum = 0.f;
        u32 pw[16];
#pragma unroll
        for (int r = 0; r < 16; ++r) {
            float p = __expf(s[r] + tsh);
            rsum += p;
            u32 ph = f2bf(p);
            u32 pl = f2bf(p - bf2f(ph));
            pw[r] = (ph << 16) | pl;
        }
        rsum += __shfl_xor(rsum, 32);
        l_run = l_run * alpha + rsum;
        m_run = m_new;
        // write P^T (packed hi|lo) to this wave's private LDS region
#pragma unroll
        for (int r = 0; r < 16; ++r) {
            const int kr = (r & 3) + ((r >> 2) << 3) + h5 * 4;
            Pp[kr * 32 + l31] = pw[r];
        }
        // rescale O
#pragma unroll
        for (int i = 0; i < 4; ++i)
#pragma unroll
            for (int r = 0; r < 16; ++r) o_[i][r] *= alpha;

        // -- wait V(t) (oldest 4 remaining), leave K(t+1)
        asm volatile("s_waitcnt vmcnt(4)" ::: "memory");
        __builtin_amdgcn_sched_barrier(0);
        __builtin_amdgcn_s_barrier();
        __builtin_amdgcn_sched_barrier(0);

        // ---- PV: O^T[d][q] += Vt * P^T   (Vh*Ph + Vl*Ph + Vh*Pl)
        const char* vb = lds + 32768;
#pragma unroll
        for (int kk2 = 0; kk2 < 2; ++kk2) {
            u32 pu[8];
            const int kbase = kk2 * 16 + h5 * 8;
#pragma unroll
            for (int j = 0; j < 8; ++j) pu[j] = Pp[(kbase + j) * 32 + l31];
            short8 pH, pL;
#pragma unroll
            for (int j = 0; j < 8; ++j) {
                pH[j] = (short)(pu[j] >> 16);
                pL[j] = (short)(pu[j] & 0xffffu);
            }
#pragma unroll
            for (int nt = 0; nt < 4; ++nt) {
                const int d = nt * 32 + l31;
                const int g = kk2 * 2 + h5;
                const int off = d * 64 + ((g ^ (d & 3)) << 4);
                short8 vh = *(const short8*)(vb + off);
                short8 vl = *(const short8*)(vb + 8192 + off);
                o_[nt] = __builtin_amdgcn_mfma_f32_32x32x16_bf16(vh, pH, o_[nt], 0, 0, 0);
                o_[nt] = __builtin_amdgcn_mfma_f32_32x32x16_bf16(vl, pH, o_[nt], 0, 0, 0);
                o_[nt] = __builtin_amdgcn_mfma_f32_32x32x16_bf16(vh, pL, o_[nt], 0, 0, 0);
            }
        }
        __builtin_amdgcn_s_barrier();     // end: K(t)/V(t) buffers now free
        __builtin_amdgcn_sched_barrier(0);
    }
    asm volatile("s_waitcnt vmcnt(0)" ::: "memory");

    // ---- epilogue: out[b][n*128+d][q], coalesced along q
    const float inv = 1.f / l_run;
#pragma unroll
    for (int nt = 0; nt < 4; ++nt)
#pragma unroll
        for (int r = 0; r < 16; ++r) {
            const int d = nt * 32 + (r & 3) + ((r >> 2) << 3) + h5 * 4;
            out[((size_t)b * 1024 + n * 128 + d) * PP + q] = o_[nt][r] * inv;
        }
}

// ============================================================================
extern "C" void kernel_launch(void* const* d_in, const int* in_sizes, int n_in,
                              void* d_out, int out_size, void* d_ws, size_t ws_size,
                              hipStream_t stream)
{
    const float* fm   = (const float*)d_in[0];
    const float* wqkv = (const float*)d_in[1];
    const float* relH = (const float*)d_in[2];
    const float* relW = (const float*)d_in[3];
    float* out = (float*)d_out;

    char* ws = (char*)d_ws;
    u16*  Qhi  = (u16*)(ws);
    u16*  Qlo  = (u16*)(ws + (16ull << 20));
    char* KIMG = ws + (32ull << 20);
    char* VIMG = ws + (64ull << 20);
    float* R   = (float*)(ws + (96ull << 20));

    qkv_kernel<<<dim3(8, 24, 8), 256, 0, stream>>>(fm, wqkv, Qhi, Qlo, KIMG, VIMG);
    rel_kernel<<<64 * 256, 256, 0, stream>>>(Qhi, Qlo, relH, relW, R);
    attn_kernel<<<dim3(8, 64), 256, 0, stream>>>(Qhi, Qlo, KIMG, VIMG, R, out);
}

// Round 4
// 501.127 us; speedup vs baseline: 3.4378x; 1.4254x over previous
//
#include <hip/hip_runtime.h>

// ---- problem constants ----
#define BATCH 8
#define CIN   512
#define NH    8
#define DH    128
#define PP    1024   // 32*32 positions
#define QK_SCALE 0.08838834764831845f  // 128^-0.5

typedef unsigned int  u32;
typedef unsigned short u16;
typedef __attribute__((ext_vector_type(8)))  short short8;
typedef __attribute__((ext_vector_type(16))) float f32x16;

typedef __attribute__((address_space(1))) const u32 GU32;
typedef __attribute__((address_space(3))) u32 LU32;

// workspace layout (bytes):
//   Qhi  [64][1024][128] u16   @ 0        (16 MB)
//   Qlo  [64][1024][128] u16   @ 16 MB    (16 MB)
//   KIMG [64*32][16384]  char  @ 32 MB    (32 MB)  per-tile: hi 8KB, lo 8KB
//   VIMG [64*32][16384]  char  @ 64 MB    (32 MB)
//   R    [64][1024][64]  f32   @ 96 MB    (16 MB)  } overlaid: FIMG dead before
//   FIMG [8*8*16][16384] char  @ 96 MB    (16 MB)  } rel_kernel writes R
//   AIMG [24*16][16384]  char  @ 112 MB   (6.3 MB)

__device__ inline u32 f2bf(float x) {            // fp32 -> bf16 (RNE)
    u32 u = __float_as_uint(x);
    return (u + 0x7fffu + ((u >> 16) & 1u)) >> 16;
}
__device__ inline float bf2f(u32 h) { return __uint_as_float(h << 16); }

__device__ inline void cvt8(const float* v, float scl, uint4& hv, uint4& lv) {
    u32 h[8], l[8];
#pragma unroll
    for (int j = 0; j < 8; ++j) {
        float x = v[j] * scl;
        u32 hb = f2bf(x);
        float hf = bf2f(hb);
        u32 lb = f2bf(x - hf);
        h[j] = hb; l[j] = lb;
    }
    hv = make_uint4(h[0] | (h[1] << 16), h[2] | (h[3] << 16),
                    h[4] | (h[5] << 16), h[6] | (h[7] << 16));
    lv = make_uint4(l[0] | (l[1] << 16), l[2] | (l[3] << 16),
                    l[4] | (l[5] << 16), l[6] | (l[7] << 16));
}

// ============================================================================
// Kernel 0a: W -> AIMG (bf16 hi/lo split, Q rows pre-scaled).
// A-chunk image [otile][chunk]: 16KB = hi 8KB + lo 8KB; byte = row*64 +
// ((g ^ (row&3))<<4), row = o&127, g = (c%32)/8.  (GEMM A-frag reads are
// then uniform 8 dwords/bank.)
// ============================================================================
__global__ __launch_bounds__(256) void wconv(
    const float* __restrict__ w, char* __restrict__ AIMG)
{
    const int gid = blockIdx.x * 256 + threadIdx.x;    // 196608 granules
    const int o  = gid >> 6;
    const int c0 = (gid & 63) << 3;
    const float scl = (o < 1024) ? QK_SCALE : 1.0f;
    float v[8];
    float4 v0 = *(const float4*)(w + (size_t)o * CIN + c0);
    float4 v1 = *(const float4*)(w + (size_t)o * CIN + c0 + 4);
    v[0]=v0.x; v[1]=v0.y; v[2]=v0.z; v[3]=v0.w;
    v[4]=v1.x; v[5]=v1.y; v[6]=v1.z; v[7]=v1.w;
    uint4 hv, lv; cvt8(v, scl, hv, lv);
    const int otile = o >> 7, row = o & 127, chunk = c0 >> 5, g = (c0 >> 3) & 3;
    char* base = AIMG + (size_t)(otile * 16 + chunk) * 16384
               + row * 64 + ((g ^ (row & 3)) << 4);
    *(uint4*)(base)        = hv;
    *(uint4*)(base + 8192) = lv;
}

// ============================================================================
// Kernel 0b: fm -> FIMG (transpose via LDS + bf16 hi/lo split).
// B-chunk image [b][ptile][chunk]: byte = p*64 + ((g ^ (p&3))<<4),
// g = (c%32)/8 — granule holds 8 consecutive c at one p.
// ============================================================================
__global__ __launch_bounds__(256) void fmconv(
    const float* __restrict__ fm, char* __restrict__ FIMG)
{
    __shared__ float Fs[32][128];
    const int t = threadIdx.x;
    const int chunk = blockIdx.x, ptile = blockIdx.y, b = blockIdx.z;
    const float* src = fm + ((size_t)(b * CIN + chunk * 32)) * PP + ptile * 128;
#pragma unroll
    for (int ii = 0; ii < 4; ++ii) {
        int idx = t + 256 * ii;                 // 1024 float4 = 32c x 128p
        int c = idx >> 5, p4 = idx & 31;
        *(float4*)(&Fs[c][p4 * 4]) = *(const float4*)(src + (size_t)c * PP + p4 * 4);
    }
    __syncthreads();
    const int p = t & 127, gb = (t >> 7) * 2;
#pragma unroll
    for (int gi = 0; gi < 2; ++gi) {
        const int g = gb + gi;
        float v[8];
#pragma unroll
        for (int j = 0; j < 8; ++j) v[j] = Fs[g * 8 + j][p];   // 2-way: free
        uint4 hv, lv; cvt8(v, 1.0f, hv, lv);
        char* base = FIMG + (size_t)((b * 8 + ptile) * 16 + chunk) * 16384
                   + p * 64 + ((g ^ (p & 3)) << 4);
        *(uint4*)(base)        = hv;
        *(uint4*)(base + 8192) = lv;
    }
}

// ============================================================================
// Kernel 1: QKV projection as split-bf16 MFMA GEMM.
// Block: 128(o) x 128(p) tile, 4 waves (2x2, 64x64 each), K=512 in 16 chunks
// of 32, double-buffered (2 x 32KB), counted vmcnt(8) pipeline.
// Per chunk per wave: 16 ds_read_b128 + 24 MFMA(32x32x16, 3-term split).
// Epilogue: acc -> swizzled fp32 LDS Cs[o][p ^ (o&31)] -> Q planes / K / V
// tile images (identical layouts to round-3 consumer kernels).
// ============================================================================
__global__ __launch_bounds__(256, 2) void qkv_gemm(
    const char* __restrict__ AIMG, const char* __restrict__ FIMG,
    u16* __restrict__ Qhi, u16* __restrict__ Qlo,
    char* __restrict__ KIMG, char* __restrict__ VIMG)
{
    __shared__ char lds[65536];       // 2 x (A 16KB | B 16KB); reused as Cs

    const int t = threadIdx.x, lane = t & 63, wid = t >> 6;
    const int l31 = lane & 31, h5 = lane >> 5;
    const int ptile = blockIdx.x, otile = blockIdx.y, b = blockIdx.z;
    const int wr = wid >> 1, wc = wid & 1;

    const char* Achunks = AIMG + (size_t)(otile * 16) * 16384;
    const char* Bchunks = FIMG + (size_t)((b * 8 + ptile) * 16) * 16384;

    const int half = wid & 1;
    const char* srcTile = (wid < 2) ? Achunks : Bchunks;
    char* dstBase0 = lds + ((wid < 2) ? 0 : 16384) + half * 8192;   // wave-uniform

    auto stageChunk = [&](int chunk, int par) {
        const char* src = srcTile + (size_t)chunk * 16384 + half * 8192 + lane * 16;
        char* dst = dstBase0 + par * 32768;
#pragma unroll
        for (int c = 0; c < 8; ++c)
            __builtin_amdgcn_global_load_lds((GU32*)(src + c * 1024),
                                             (LU32*)(dst + c * 1024), 16, 0, 0);
    };

    f32x16 acc[2][2];
#pragma unroll
    for (int i = 0; i < 2; ++i)
#pragma unroll
        for (int j = 0; j < 2; ++j)
#pragma unroll
            for (int r = 0; r < 16; ++r) acc[i][j][r] = 0.f;

    auto computeChunk = [&](int par) {
        const char* Abuf = lds + par * 32768;
        const char* Bbuf = Abuf + 16384;
#pragma unroll
        for (int ks = 0; ks < 2; ++ks) {
            short8 a_h[2], a_l[2], b_h[2], b_l[2];
#pragma unroll
            for (int ot = 0; ot < 2; ++ot) {
                const int row = wr * 64 + ot * 32 + l31;
                const int off = row * 64 + (((ks * 2 + h5) ^ (row & 3)) << 4);
                a_h[ot] = *(const short8*)(Abuf + off);
                a_l[ot] = *(const short8*)(Abuf + 8192 + off);
            }
#pragma unroll
            for (int pt = 0; pt < 2; ++pt) {
                const int col = wc * 64 + pt * 32 + l31;
                const int off = col * 64 + (((ks * 2 + h5) ^ (col & 3)) << 4);
                b_h[pt] = *(const short8*)(Bbuf + off);
                b_l[pt] = *(const short8*)(Bbuf + 8192 + off);
            }
#pragma unroll
            for (int ot = 0; ot < 2; ++ot)
#pragma unroll
                for (int pt = 0; pt < 2; ++pt) {
                    acc[ot][pt] = __builtin_amdgcn_mfma_f32_32x32x16_bf16(a_h[ot], b_h[pt], acc[ot][pt], 0, 0, 0);
                    acc[ot][pt] = __builtin_amdgcn_mfma_f32_32x32x16_bf16(a_h[ot], b_l[pt], acc[ot][pt], 0, 0, 0);
                    acc[ot][pt] = __builtin_amdgcn_mfma_f32_32x32x16_bf16(a_l[ot], b_h[pt], acc[ot][pt], 0, 0, 0);
                }
        }
    };

    stageChunk(0, 0);
    for (int ch = 0; ch < 15; ++ch) {
        stageChunk(ch + 1, (ch + 1) & 1);
        asm volatile("s_waitcnt vmcnt(8)" ::: "memory");
        __builtin_amdgcn_sched_barrier(0);
        __builtin_amdgcn_s_barrier();
        __builtin_amdgcn_sched_barrier(0);
        computeChunk(ch & 1);
        __builtin_amdgcn_s_barrier();
        __builtin_amdgcn_sched_barrier(0);
    }
    asm volatile("s_waitcnt vmcnt(0)" ::: "memory");
    __builtin_amdgcn_sched_barrier(0);
    __builtin_amdgcn_s_barrier();
    __builtin_amdgcn_sched_barrier(0);
    computeChunk(1);                  // chunk 15
    __syncthreads();                  // all frag reads done; LDS -> Cs

    // ---- restage C tile (fp32, XOR-swizzled): Cs[o*128 + (p ^ (o&31))]
    float* Cs = (float*)lds;
#pragma unroll
    for (int ot = 0; ot < 2; ++ot)
#pragma unroll
        for (int pt = 0; pt < 2; ++pt)
#pragma unroll
            for (int r = 0; r < 16; ++r) {
                const int o = wr * 64 + ot * 32 + (r & 3) + 8 * (r >> 2) + 4 * h5;
                const int p = wc * 64 + pt * 32 + l31;
                Cs[o * 128 + (p ^ (o & 31))] = acc[ot][pt][r];
            }
    __syncthreads();

    const int tsel = otile >> 3;      // 0=Q 1=K 2=V
    const int n    = otile & 7;
    const int bn   = b * NH + n;

    if (tsel == 0) {
        // Q planes: granule = 8 consecutive d at one p
        const int d0 = (t & 15) * 8, prow = t >> 4;
#pragma unroll
        for (int i = 0; i < 8; ++i) {
            const int p = prow + 16 * i;
            float v[8];
#pragma unroll
            for (int j = 0; j < 8; ++j)
                v[j] = Cs[(d0 + j) * 128 + (p ^ ((d0 + j) & 31))];
            uint4 hv, lv; cvt8(v, 1.0f, hv, lv);
            const size_t off = ((size_t)bn * PP + ptile * 128 + p) * DH + d0;
            *(uint4*)(Qhi + off) = hv;
            *(uint4*)(Qlo + off) = lv;
        }
    } else if (tsel == 1) {
        // K images: granule = 8 consecutive d at one key, slot (d0/8)^(r&15)
        const int d0 = (t & 15) * 8, prow = t >> 4;
#pragma unroll
        for (int i = 0; i < 8; ++i) {
            const int p = prow + 16 * i;
            float v[8];
#pragma unroll
            for (int j = 0; j < 8; ++j)
                v[j] = Cs[(d0 + j) * 128 + (p ^ ((d0 + j) & 31))];
            uint4 hv, lv; cvt8(v, 1.0f, hv, lv);
            const int kt = ptile * 4 + (p >> 5), r32 = p & 31;
            char* base = KIMG + ((size_t)(bn * 32 + kt) << 14)
                       + r32 * 256 + (((d0 >> 3) ^ (r32 & 15)) << 4);
            *(uint4*)(base)        = hv;
            *(uint4*)(base + 8192) = lv;
        }
    } else {
        // V images: granule = 8 consecutive keys at one d, slot g^(d&3)
        const int g = t & 3, dbase = t >> 2;
#pragma unroll
        for (int i = 0; i < 2; ++i) {
            const int d = dbase + 64 * i;
#pragma unroll
            for (int ks = 0; ks < 4; ++ks) {
                const int p0 = ks * 32 + g * 8;
                float v[8];
#pragma unroll
                for (int j = 0; j < 8; ++j)
                    v[j] = Cs[d * 128 + ((p0 + j) ^ (d & 31))];
                uint4 hv, lv; cvt8(v, 1.0f, hv, lv);
                char* base = VIMG + ((size_t)(bn * 32 + ptile * 4 + ks) << 14)
                           + d * 64 + ((g ^ (d & 3)) << 4);
                *(uint4*)(base)        = hv;
                *(uint4*)(base + 8192) = lv;
            }
        }
    }
}

// ============================================================================
// Kernel 2: relative-position dots (fp32), reading Q from hi/lo planes.
// ============================================================================
__global__ __launch_bounds__(256) void rel_kernel(
    const u16* __restrict__ Qhi, const u16* __restrict__ Qlo,
    const float* __restrict__ relH, const float* __restrict__ relW,
    float* __restrict__ R)
{
    __shared__ float Qs[4][128];
    const int t     = threadIdx.x;
    const int blk   = blockIdx.x;        // 64 * 256 blocks
    const int bn    = blk >> 8;
    const int pbase = (blk & 255) * 4;

    if (t < 64) {
        const int row = t >> 4, d0 = (t & 15) * 8;
        const size_t qoff = ((size_t)bn * PP + pbase + row) * DH + d0;
        uint4 hv = *(const uint4*)(Qhi + qoff);
        uint4 lv = *(const uint4*)(Qlo + qoff);
        const u32 hw[4] = {hv.x, hv.y, hv.z, hv.w};
        const u32 lw[4] = {lv.x, lv.y, lv.z, lv.w};
#pragma unroll
        for (int w2 = 0; w2 < 4; ++w2) {
            Qs[row][d0 + w2*2]     = bf2f(hw[w2] & 0xffffu) + bf2f(lw[w2] & 0xffffu);
            Qs[row][d0 + w2*2 + 1] = bf2f(hw[w2] >> 16)     + bf2f(lw[w2] >> 16);
        }
    }
    __syncthreads();

    const int lp = t >> 6, j = t & 63;
    const int p = pbase + lp;
    const int h = p >> 5, wq = p & 31;
    const float* rel = (j < 32) ? (relH + (size_t)(j - h + 31) * DH)
                                : (relW + (size_t)((j - 32) - wq + 31) * DH);
    const float4* q4 = (const float4*)(&Qs[lp][0]);
    const float4* r4 = (const float4*)rel;
    float s = 0.f;
#pragma unroll
    for (int d = 0; d < 32; ++d) {
        float4 a = q4[d], bv = r4[d];
        s += a.x * bv.x + a.y * bv.y + a.z * bv.z + a.w * bv.w;
    }
    R[((size_t)bn * PP + p) * 64 + j] = s;
}

// ============================================================================
// Kernel 3: split-bf16 MFMA flash attention (unchanged from round 3).
// ============================================================================
__global__ __launch_bounds__(256, 2) void attn_kernel(
    const u16* __restrict__ Qhi, const u16* __restrict__ Qlo,
    const char* __restrict__ KIMG, const char* __restrict__ VIMG,
    const float* __restrict__ R, float* __restrict__ out)
{
    __shared__ char lds[81920];

    const int t    = threadIdx.x;
    const int lane = t & 63, wid = t >> 6;
    const int bn = blockIdx.y, q0 = blockIdx.x * 128;
    const int b  = bn >> 3,  n = bn & 7;
    const int l31 = lane & 31, h5 = lane >> 5;
    const int q_local = wid * 32 + l31;
    const int q = q0 + q_local;

    short8 qh[8], ql[8];
    {
        const u16* qrh = Qhi + ((size_t)bn * PP + q) * DH + h5 * 8;
        const u16* qrl = Qlo + ((size_t)bn * PP + q) * DH + h5 * 8;
#pragma unroll
        for (int kk = 0; kk < 8; ++kk) {
            qh[kk] = *(const short8*)(qrh + kk * 16);
            ql[kk] = *(const short8*)(qrl + kk * 16);
        }
    }
    float R2a[16];
    {
        const float* r2p = R + ((size_t)bn * PP + q) * 64 + 32 + h5 * 4;
#pragma unroll
        for (int m_ = 0; m_ < 4; ++m_) {
            float4 v = *(const float4*)(r2p + m_ * 8);
            R2a[m_*4+0] = v.x; R2a[m_*4+1] = v.y; R2a[m_*4+2] = v.z; R2a[m_*4+3] = v.w;
        }
    }
    float* R1p = (float*)(lds + 65536);
    {
#pragma unroll
        for (int r = 0; r < 4; ++r) {
            int idx = t + 256 * r;
            int row = idx >> 3, c4 = (idx & 7) * 4;
            float4 v = *(const float4*)(R + ((size_t)bn * PP + q0 + row) * 64 + c4);
            R1p[row * 32 + ((c4 + 0) ^ (row & 31))] = v.x;
            R1p[row * 32 + ((c4 + 1) ^ (row & 31))] = v.y;
            R1p[row * 32 + ((c4 + 2) ^ (row & 31))] = v.z;
            R1p[row * 32 + ((c4 + 3) ^ (row & 31))] = v.w;
        }
    }

    auto issueK = [&](int kt, int par) {
        const char* src = KIMG + (((size_t)bn * 32 + kt) << 14) + wid * 4096 + lane * 16;
        const char* dst = lds + par * 16384 + wid * 4096;
#pragma unroll
        for (int c = 0; c < 4; ++c)
            __builtin_amdgcn_global_load_lds((GU32*)(src + c * 1024),
                                             (LU32*)(dst + c * 1024), 16, 0, 0);
    };
    auto issueV = [&](int kt) {
        const char* src = VIMG + (((size_t)bn * 32 + kt) << 14) + wid * 4096 + lane * 16;
        const char* dst = lds + 32768 + wid * 4096;
#pragma unroll
        for (int c = 0; c < 4; ++c)
            __builtin_amdgcn_global_load_lds((GU32*)(src + c * 1024),
                                             (LU32*)(dst + c * 1024), 16, 0, 0);
    };

    issueK(0, 0);
    asm volatile("s_waitcnt lgkmcnt(0)" ::: "memory");
    __builtin_amdgcn_s_barrier();
    __builtin_amdgcn_sched_barrier(0);

    f32x16 o_[4];
#pragma unroll
    for (int i = 0; i < 4; ++i)
#pragma unroll
        for (int r = 0; r < 16; ++r) o_[i][r] = 0.f;

    float m_run = -1e30f, l_run = 0.f;
    u32* Pp = (u32*)(lds + 49152 + wid * 4096);

    for (int kt = 0; kt < 32; ++kt) {
        const int par = kt & 1;
        issueV(kt);
        issueK((kt + 1) & 31, par ^ 1);
        asm volatile("s_waitcnt vmcnt(8)" ::: "memory");
        __builtin_amdgcn_sched_barrier(0);
        __builtin_amdgcn_s_barrier();
        __builtin_amdgcn_sched_barrier(0);

        f32x16 s;
#pragma unroll
        for (int r = 0; r < 16; ++r) s[r] = 0.f;
        const char* kb = lds + par * 16384;
#pragma unroll
        for (int kk = 0; kk < 8; ++kk) {
            const int g = kk * 2 + h5;
            const int off = l31 * 256 + ((g ^ (l31 & 15)) << 4);
            short8 kh = *(const short8*)(kb + off);
            short8 kl = *(const short8*)(kb + 8192 + off);
            s = __builtin_amdgcn_mfma_f32_32x32x16_bf16(kh, qh[kk], s, 0, 0, 0);
            s = __builtin_amdgcn_mfma_f32_32x32x16_bf16(kh, ql[kk], s, 0, 0, 0);
            s = __builtin_amdgcn_mfma_f32_32x32x16_bf16(kl, qh[kk], s, 0, 0, 0);
        }
        const float r1 = R1p[q_local * 32 + (kt ^ l31)];

        float mx = -1e30f;
#pragma unroll
        for (int r = 0; r < 16; ++r) {
            s[r] += R2a[r];
            mx = fmaxf(mx, s[r]);
        }
        mx = fmaxf(mx, __shfl_xor(mx, 32));
        const float pmax  = mx + r1;
        const float m_new = fmaxf(m_run, pmax);
        const float alpha = __expf(m_run - m_new);
        const float tsh   = r1 - m_new;
        float rsum = 0.f;
        u32 pw[16];
#pragma unroll
        for (int r = 0; r < 16; ++r) {
            float p = __expf(s[r] + tsh);
            rsum += p;
            u32 ph = f2bf(p);
            u32 pl = f2bf(p - bf2f(ph));
            pw[r] = (ph << 16) | pl;
        }
        rsum += __shfl_xor(rsum, 32);
        l_run = l_run * alpha + rsum;
        m_run = m_new;
#pragma unroll
        for (int r = 0; r < 16; ++r) {
            const int kr = (r & 3) + ((r >> 2) << 3) + h5 * 4;
            Pp[kr * 32 + l31] = pw[r];
        }
#pragma unroll
        for (int i = 0; i < 4; ++i)
#pragma unroll
            for (int r = 0; r < 16; ++r) o_[i][r] *= alpha;

        asm volatile("s_waitcnt vmcnt(4)" ::: "memory");
        __builtin_amdgcn_sched_barrier(0);
        __builtin_amdgcn_s_barrier();
        __builtin_amdgcn_sched_barrier(0);

        const char* vb = lds + 32768;
#pragma unroll
        for (int kk2 = 0; kk2 < 2; ++kk2) {
            u32 pu[8];
            const int kbase = kk2 * 16 + h5 * 8;
#pragma unroll
            for (int j = 0; j < 8; ++j) pu[j] = Pp[(kbase + j) * 32 + l31];
            short8 pH, pL;
#pragma unroll
            for (int j = 0; j < 8; ++j) {
                pH[j] = (short)(pu[j] >> 16);
                pL[j] = (short)(pu[j] & 0xffffu);
            }
#pragma unroll
            for (int nt = 0; nt < 4; ++nt) {
                const int d = nt * 32 + l31;
                const int g = kk2 * 2 + h5;
                const int off = d * 64 + ((g ^ (d & 3)) << 4);
                short8 vh = *(const short8*)(vb + off);
                short8 vl = *(const short8*)(vb + 8192 + off);
                o_[nt] = __builtin_amdgcn_mfma_f32_32x32x16_bf16(vh, pH, o_[nt], 0, 0, 0);
                o_[nt] = __builtin_amdgcn_mfma_f32_32x32x16_bf16(vl, pH, o_[nt], 0, 0, 0);
                o_[nt] = __builtin_amdgcn_mfma_f32_32x32x16_bf16(vh, pL, o_[nt], 0, 0, 0);
            }
        }
        __builtin_amdgcn_s_barrier();
        __builtin_amdgcn_sched_barrier(0);
    }
    asm volatile("s_waitcnt vmcnt(0)" ::: "memory");

    const float inv = 1.f / l_run;
#pragma unroll
    for (int nt = 0; nt < 4; ++nt)
#pragma unroll
        for (int r = 0; r < 16; ++r) {
            const int d = nt * 32 + (r & 3) + ((r >> 2) << 3) + h5 * 4;
            out[((size_t)b * 1024 + n * 128 + d) * PP + q] = o_[nt][r] * inv;
        }
}

// ============================================================================
extern "C" void kernel_launch(void* const* d_in, const int* in_sizes, int n_in,
                              void* d_out, int out_size, void* d_ws, size_t ws_size,
                              hipStream_t stream)
{
    const float* fm   = (const float*)d_in[0];
    const float* wqkv = (const float*)d_in[1];
    const float* relH = (const float*)d_in[2];
    const float* relW = (const float*)d_in[3];
    float* out = (float*)d_out;

    char* ws = (char*)d_ws;
    u16*  Qhi  = (u16*)(ws);
    u16*  Qlo  = (u16*)(ws + (16ull << 20));
    char* KIMG = ws + (32ull << 20);
    char* VIMG = ws + (64ull << 20);
    float* R   = (float*)(ws + (96ull << 20));
    char* FIMG = ws + (96ull << 20);              // overlays R (dead before rel)
    char* AIMG = ws + (112ull << 20);

    wconv <<<768, 256, 0, stream>>>(wqkv, AIMG);
    fmconv<<<dim3(16, 8, 8), 256, 0, stream>>>(fm, FIMG);
    qkv_gemm<<<dim3(8, 24, 8), 256, 0, stream>>>(AIMG, FIMG, Qhi, Qlo, KIMG, VIMG);
    rel_kernel<<<64 * 256, 256, 0, stream>>>(Qhi, Qlo, relH, relW, R);
    attn_kernel<<<dim3(8, 64), 256, 0, stream>>>(Qhi, Qlo, KIMG, VIMG, R, out);
}

// Round 5
// 304.927 us; speedup vs baseline: 5.6498x; 1.6434x over previous
//
#include <hip/hip_runtime.h>

// ---- problem constants ----
#define BATCH 8
#define CIN   512
#define NH    8
#define DH    128
#define PP    1024   // 32*32 positions
#define QK_SCALE 0.08838834764831845f  // 128^-0.5

typedef unsigned int  u32;
typedef unsigned short u16;
typedef __attribute__((ext_vector_type(8)))  short short8;
typedef __attribute__((ext_vector_type(16))) float f32x16;

typedef __attribute__((address_space(1))) const u32 GU32;
typedef __attribute__((address_space(3))) u32 LU32;

// workspace layout (bytes):
//   Qhi    [64][1024][128] u16   @ 0        (16 MB)
//   Qlo    [64][1024][128] u16   @ 16 MB    (16 MB)
//   KIMG   [64*32][16384]  char  @ 32 MB    (32 MB)  per-tile: hi 8KB, lo 8KB
//   VIMG   [64*32][16384]  char  @ 64 MB    (32 MB)
//   R      [64][1024][64]  f32   @ 96 MB    (16 MB)  } overlaid: FIMG dead before
//   FIMG   [8*8*16][16384] char  @ 96 MB    (16 MB)  } rel_gemm writes R
//   AIMG   [24*16][16384]  char  @ 112 MB   (6.3 MB)
//   RELIMG [128 rows]      char  @ 119 MB   (64 KB)  relcat image hi 32K | lo 32K

__device__ inline u32 f2bf(float x) {            // fp32 -> bf16 (RNE)
    u32 u = __float_as_uint(x);
    return (u + 0x7fffu + ((u >> 16) & 1u)) >> 16;
}
__device__ inline float bf2f(u32 h) { return __uint_as_float(h << 16); }

__device__ inline void cvt8(const float* v, float scl, uint4& hv, uint4& lv) {
    u32 h[8], l[8];
#pragma unroll
    for (int j = 0; j < 8; ++j) {
        float x = v[j] * scl;
        u32 hb = f2bf(x);
        float hf = bf2f(hb);
        u32 lb = f2bf(x - hf);
        h[j] = hb; l[j] = lb;
    }
    hv = make_uint4(h[0] | (h[1] << 16), h[2] | (h[3] << 16),
                    h[4] | (h[5] << 16), h[6] | (h[7] << 16));
    lv = make_uint4(l[0] | (l[1] << 16), l[2] | (l[3] << 16),
                    l[4] | (l[5] << 16), l[6] | (l[7] << 16));
}

// ============================================================================
// Kernel 0a: W -> AIMG (bf16 hi/lo split, Q rows pre-scaled).
// ============================================================================
__global__ __launch_bounds__(256) void wconv(
    const float* __restrict__ w, char* __restrict__ AIMG)
{
    const int gid = blockIdx.x * 256 + threadIdx.x;    // 196608 granules
    const int o  = gid >> 6;
    const int c0 = (gid & 63) << 3;
    const float scl = (o < 1024) ? QK_SCALE : 1.0f;
    float v[8];
    float4 v0 = *(const float4*)(w + (size_t)o * CIN + c0);
    float4 v1 = *(const float4*)(w + (size_t)o * CIN + c0 + 4);
    v[0]=v0.x; v[1]=v0.y; v[2]=v0.z; v[3]=v0.w;
    v[4]=v1.x; v[5]=v1.y; v[6]=v1.z; v[7]=v1.w;
    uint4 hv, lv; cvt8(v, scl, hv, lv);
    const int otile = o >> 7, row = o & 127, chunk = c0 >> 5, g = (c0 >> 3) & 3;
    char* base = AIMG + (size_t)(otile * 16 + chunk) * 16384
               + row * 64 + ((g ^ (row & 3)) << 4);
    *(uint4*)(base)        = hv;
    *(uint4*)(base + 8192) = lv;
}

// ============================================================================
// Kernel 0b: fm -> FIMG (transpose via LDS + bf16 hi/lo split).
// ============================================================================
__global__ __launch_bounds__(256) void fmconv(
    const float* __restrict__ fm, char* __restrict__ FIMG)
{
    __shared__ float Fs[32][128];
    const int t = threadIdx.x;
    const int chunk = blockIdx.x, ptile = blockIdx.y, b = blockIdx.z;
    const float* src = fm + ((size_t)(b * CIN + chunk * 32)) * PP + ptile * 128;
#pragma unroll
    for (int ii = 0; ii < 4; ++ii) {
        int idx = t + 256 * ii;                 // 1024 float4 = 32c x 128p
        int c = idx >> 5, p4 = idx & 31;
        *(float4*)(&Fs[c][p4 * 4]) = *(const float4*)(src + (size_t)c * PP + p4 * 4);
    }
    __syncthreads();
    const int p = t & 127, gb = (t >> 7) * 2;
#pragma unroll
    for (int gi = 0; gi < 2; ++gi) {
        const int g = gb + gi;
        float v[8];
#pragma unroll
        for (int j = 0; j < 8; ++j) v[j] = Fs[g * 8 + j][p];   // 2-way: free
        uint4 hv, lv; cvt8(v, 1.0f, hv, lv);
        char* base = FIMG + (size_t)((b * 8 + ptile) * 16 + chunk) * 16384
                   + p * 64 + ((g ^ (p & 3)) << 4);
        *(uint4*)(base)        = hv;
        *(uint4*)(base + 8192) = lv;
    }
}

// ============================================================================
// Kernel 0c: relH/relW -> RELIMG (relcat image, 128 rows x 128 d, split bf16).
// rows 0..62 = relH; 63..125 = relW; 126..127 = zeros.
// byte = r*256 + ((g ^ (r&15))<<4); hi plane 32KB, lo at +32768.
// ============================================================================
__global__ __launch_bounds__(256) void relprep(
    const float* __restrict__ relH, const float* __restrict__ relW,
    char* __restrict__ RELIMG)
{
    const int idx = blockIdx.x * 256 + threadIdx.x;   // 2048 granules
    const int r = idx >> 4, g = idx & 15;
    float v[8];
    if (r < 63) {
        float4 v0 = *(const float4*)(relH + (size_t)r * DH + g * 8);
        float4 v1 = *(const float4*)(relH + (size_t)r * DH + g * 8 + 4);
        v[0]=v0.x; v[1]=v0.y; v[2]=v0.z; v[3]=v0.w;
        v[4]=v1.x; v[5]=v1.y; v[6]=v1.z; v[7]=v1.w;
    } else if (r < 126) {
        float4 v0 = *(const float4*)(relW + (size_t)(r - 63) * DH + g * 8);
        float4 v1 = *(const float4*)(relW + (size_t)(r - 63) * DH + g * 8 + 4);
        v[0]=v0.x; v[1]=v0.y; v[2]=v0.z; v[3]=v0.w;
        v[4]=v1.x; v[5]=v1.y; v[6]=v1.z; v[7]=v1.w;
    } else {
#pragma unroll
        for (int j = 0; j < 8; ++j) v[j] = 0.f;
    }
    uint4 hv, lv; cvt8(v, 1.0f, hv, lv);
    char* base = RELIMG + r * 256 + ((g ^ (r & 15)) << 4);
    *(uint4*)(base)         = hv;
    *(uint4*)(base + 32768) = lv;
}

// ============================================================================
// Kernel 1: QKV projection as split-bf16 MFMA GEMM (unchanged from round 4).
// ============================================================================
__global__ __launch_bounds__(256, 2) void qkv_gemm(
    const char* __restrict__ AIMG, const char* __restrict__ FIMG,
    u16* __restrict__ Qhi, u16* __restrict__ Qlo,
    char* __restrict__ KIMG, char* __restrict__ VIMG)
{
    __shared__ char lds[65536];       // 2 x (A 16KB | B 16KB); reused as Cs

    const int t = threadIdx.x, lane = t & 63, wid = t >> 6;
    const int l31 = lane & 31, h5 = lane >> 5;
    const int ptile = blockIdx.x, otile = blockIdx.y, b = blockIdx.z;
    const int wr = wid >> 1, wc = wid & 1;

    const char* Achunks = AIMG + (size_t)(otile * 16) * 16384;
    const char* Bchunks = FIMG + (size_t)((b * 8 + ptile) * 16) * 16384;

    const int half = wid & 1;
    const char* srcTile = (wid < 2) ? Achunks : Bchunks;
    char* dstBase0 = lds + ((wid < 2) ? 0 : 16384) + half * 8192;   // wave-uniform

    auto stageChunk = [&](int chunk, int par) {
        const char* src = srcTile + (size_t)chunk * 16384 + half * 8192 + lane * 16;
        char* dst = dstBase0 + par * 32768;
#pragma unroll
        for (int c = 0; c < 8; ++c)
            __builtin_amdgcn_global_load_lds((GU32*)(src + c * 1024),
                                             (LU32*)(dst + c * 1024), 16, 0, 0);
    };

    f32x16 acc[2][2];
#pragma unroll
    for (int i = 0; i < 2; ++i)
#pragma unroll
        for (int j = 0; j < 2; ++j)
#pragma unroll
            for (int r = 0; r < 16; ++r) acc[i][j][r] = 0.f;

    auto computeChunk = [&](int par) {
        const char* Abuf = lds + par * 32768;
        const char* Bbuf = Abuf + 16384;
#pragma unroll
        for (int ks = 0; ks < 2; ++ks) {
            short8 a_h[2], a_l[2], b_h[2], b_l[2];
#pragma unroll
            for (int ot = 0; ot < 2; ++ot) {
                const int row = wr * 64 + ot * 32 + l31;
                const int off = row * 64 + (((ks * 2 + h5) ^ (row & 3)) << 4);
                a_h[ot] = *(const short8*)(Abuf + off);
                a_l[ot] = *(const short8*)(Abuf + 8192 + off);
            }
#pragma unroll
            for (int pt = 0; pt < 2; ++pt) {
                const int col = wc * 64 + pt * 32 + l31;
                const int off = col * 64 + (((ks * 2 + h5) ^ (col & 3)) << 4);
                b_h[pt] = *(const short8*)(Bbuf + off);
                b_l[pt] = *(const short8*)(Bbuf + 8192 + off);
            }
#pragma unroll
            for (int ot = 0; ot < 2; ++ot)
#pragma unroll
                for (int pt = 0; pt < 2; ++pt) {
                    acc[ot][pt] = __builtin_amdgcn_mfma_f32_32x32x16_bf16(a_h[ot], b_h[pt], acc[ot][pt], 0, 0, 0);
                    acc[ot][pt] = __builtin_amdgcn_mfma_f32_32x32x16_bf16(a_h[ot], b_l[pt], acc[ot][pt], 0, 0, 0);
                    acc[ot][pt] = __builtin_amdgcn_mfma_f32_32x32x16_bf16(a_l[ot], b_h[pt], acc[ot][pt], 0, 0, 0);
                }
        }
    };

    stageChunk(0, 0);
    for (int ch = 0; ch < 15; ++ch) {
        stageChunk(ch + 1, (ch + 1) & 1);
        asm volatile("s_waitcnt vmcnt(8)" ::: "memory");
        __builtin_amdgcn_sched_barrier(0);
        __builtin_amdgcn_s_barrier();
        __builtin_amdgcn_sched_barrier(0);
        computeChunk(ch & 1);
        __builtin_amdgcn_s_barrier();
        __builtin_amdgcn_sched_barrier(0);
    }
    asm volatile("s_waitcnt vmcnt(0)" ::: "memory");
    __builtin_amdgcn_sched_barrier(0);
    __builtin_amdgcn_s_barrier();
    __builtin_amdgcn_sched_barrier(0);
    computeChunk(1);                  // chunk 15
    __syncthreads();                  // all frag reads done; LDS -> Cs

    // ---- restage C tile (fp32, XOR-swizzled): Cs[o*128 + (p ^ (o&31))]
    float* Cs = (float*)lds;
#pragma unroll
    for (int ot = 0; ot < 2; ++ot)
#pragma unroll
        for (int pt = 0; pt < 2; ++pt)
#pragma unroll
            for (int r = 0; r < 16; ++r) {
                const int o = wr * 64 + ot * 32 + (r & 3) + 8 * (r >> 2) + 4 * h5;
                const int p = wc * 64 + pt * 32 + l31;
                Cs[o * 128 + (p ^ (o & 31))] = acc[ot][pt][r];
            }
    __syncthreads();

    const int tsel = otile >> 3;      // 0=Q 1=K 2=V
    const int n    = otile & 7;
    const int bn   = b * NH + n;

    if (tsel == 0) {
        const int d0 = (t & 15) * 8, prow = t >> 4;
#pragma unroll
        for (int i = 0; i < 8; ++i) {
            const int p = prow + 16 * i;
            float v[8];
#pragma unroll
            for (int j = 0; j < 8; ++j)
                v[j] = Cs[(d0 + j) * 128 + (p ^ ((d0 + j) & 31))];
            uint4 hv, lv; cvt8(v, 1.0f, hv, lv);
            const size_t off = ((size_t)bn * PP + ptile * 128 + p) * DH + d0;
            *(uint4*)(Qhi + off) = hv;
            *(uint4*)(Qlo + off) = lv;
        }
    } else if (tsel == 1) {
        const int d0 = (t & 15) * 8, prow = t >> 4;
#pragma unroll
        for (int i = 0; i < 8; ++i) {
            const int p = prow + 16 * i;
            float v[8];
#pragma unroll
            for (int j = 0; j < 8; ++j)
                v[j] = Cs[(d0 + j) * 128 + (p ^ ((d0 + j) & 31))];
            uint4 hv, lv; cvt8(v, 1.0f, hv, lv);
            const int kt = ptile * 4 + (p >> 5), r32 = p & 31;
            char* base = KIMG + ((size_t)(bn * 32 + kt) << 14)
                       + r32 * 256 + (((d0 >> 3) ^ (r32 & 15)) << 4);
            *(uint4*)(base)        = hv;
            *(uint4*)(base + 8192) = lv;
        }
    } else {
        const int g = t & 3, dbase = t >> 2;
#pragma unroll
        for (int i = 0; i < 2; ++i) {
            const int d = dbase + 64 * i;
#pragma unroll
            for (int ks = 0; ks < 4; ++ks) {
                const int p0 = ks * 32 + g * 8;
                float v[8];
#pragma unroll
                for (int j = 0; j < 8; ++j)
                    v[j] = Cs[d * 128 + ((p0 + j) ^ (d & 31))];
                uint4 hv, lv; cvt8(v, 1.0f, hv, lv);
                char* base = VIMG + ((size_t)(bn * 32 + ptile * 4 + ks) << 14)
                           + d * 64 + ((g ^ (d & 3)) << 4);
                *(uint4*)(base)        = hv;
                *(uint4*)(base + 8192) = lv;
            }
        }
    }
}

// ============================================================================
// Kernel 2: rel logits as split-bf16 MFMA GEMM + in-LDS window scatter.
// Block = (128-p tile, bn); 4 waves; C[j' 0..127][p 0..127] per block.
// LDS 128KB: relcat image (64K, staged linear) | Q images 4x16K (reg-staged,
// swizzled). Cs[128][132] fp32 overlays after compute.
// R[bn][p][j] = C[j + 31 - h][p] (j<32)  /  C[j + 62 - w][p] (j>=32).
// ============================================================================
__global__ __launch_bounds__(256, 1) void rel_gemm(
    const u16* __restrict__ Qhi, const u16* __restrict__ Qlo,
    const char* __restrict__ RELIMG, float* __restrict__ R)
{
    __shared__ char lds[131072];
    const int t = threadIdx.x, lane = t & 63, wid = t >> 6;
    const int l31 = lane & 31, h5 = lane >> 5;
    const int bn = blockIdx.y, p0 = blockIdx.x * 128;

    // stage relcat image (64 KB linear copy; layout pre-swizzled in global)
    {
        const char* src = RELIMG + wid * 16384 + lane * 16;
        char* dst = lds + wid * 16384;
#pragma unroll
        for (int c = 0; c < 16; ++c)
            __builtin_amdgcn_global_load_lds((GU32*)(src + c * 1024),
                                             (LU32*)(dst + c * 1024), 16, 0, 0);
    }
    // reg-stage Q (coalesced global read -> swizzled ds_write)
#pragma unroll
    for (int pt = 0; pt < 4; ++pt) {
#pragma unroll
        for (int half = 0; half < 2; ++half) {
            const u16* srcp = (half ? Qlo : Qhi) + ((size_t)bn * PP + p0 + pt * 32) * DH;
            char* dstb = lds + 65536 + pt * 16384 + half * 8192;
#pragma unroll
            for (int ii = 0; ii < 2; ++ii) {
                const int f = t + 256 * ii;              // granule 0..511
                const int p = f >> 4, g = f & 15;
                uint4 v = *(const uint4*)((const char*)srcp + f * 16);
                *(uint4*)(dstb + p * 256 + ((g ^ (p & 15)) << 4)) = v;
            }
        }
    }
    asm volatile("s_waitcnt vmcnt(0) lgkmcnt(0)" ::: "memory");
    __builtin_amdgcn_s_barrier();
    __builtin_amdgcn_sched_barrier(0);

    f32x16 acc[4];
#pragma unroll
    for (int i = 0; i < 4; ++i)
#pragma unroll
        for (int r = 0; r < 16; ++r) acc[i][r] = 0.f;

    const int rrow = wid * 32 + l31;
#pragma unroll
    for (int kk = 0; kk < 8; ++kk) {
        const int g = kk * 2 + h5;
        const int aoff = rrow * 256 + ((g ^ (rrow & 15)) << 4);
        short8 ah = *(const short8*)(lds + aoff);
        short8 al = *(const short8*)(lds + 32768 + aoff);
        const int boff = l31 * 256 + ((g ^ (l31 & 15)) << 4);
#pragma unroll
        for (int pt = 0; pt < 4; ++pt) {
            const char* bb = lds + 65536 + pt * 16384;
            short8 bh = *(const short8*)(bb + boff);
            short8 bl = *(const short8*)(bb + 8192 + boff);
            acc[pt] = __builtin_amdgcn_mfma_f32_32x32x16_bf16(ah, bh, acc[pt], 0, 0, 0);
            acc[pt] = __builtin_amdgcn_mfma_f32_32x32x16_bf16(ah, bl, acc[pt], 0, 0, 0);
            acc[pt] = __builtin_amdgcn_mfma_f32_32x32x16_bf16(al, bh, acc[pt], 0, 0, 0);
        }
    }
    __syncthreads();                  // all LDS reads done -> overlay Cs

    float* Cs = (float*)lds;          // [128 j'][132] padded
#pragma unroll
    for (int pt = 0; pt < 4; ++pt)
#pragma unroll
        for (int r = 0; r < 16; ++r) {
            const int jr = wid * 32 + (r & 3) + 8 * (r >> 2) + 4 * h5;
            Cs[jr * 132 + pt * 32 + l31] = acc[pt][r];
        }
    __syncthreads();

    // window scatter: thread = (p local, half of j)
    const int pl = t >> 1, jh = t & 1;
    const int pg = p0 + pl, hq = pg >> 5, wq = pg & 31;
    const int base = jh ? (94 - wq) : (31 - hq);
    float* dst = R + ((size_t)bn * PP + pg) * 64 + jh * 32;
#pragma unroll
    for (int j4 = 0; j4 < 8; ++j4) {
        float4 v;
        v.x = Cs[(base + j4 * 4 + 0) * 132 + pl];
        v.y = Cs[(base + j4 * 4 + 1) * 132 + pl];
        v.z = Cs[(base + j4 * 4 + 2) * 132 + pl];
        v.w = Cs[(base + j4 * 4 + 3) * 132 + pl];
        *(float4*)(dst + j4 * 4) = v;
    }
}

// ============================================================================
// Kernel 3: split-bf16 MFMA flash attention (unchanged from round 3).
// ============================================================================
__global__ __launch_bounds__(256, 2) void attn_kernel(
    const u16* __restrict__ Qhi, const u16* __restrict__ Qlo,
    const char* __restrict__ KIMG, const char* __restrict__ VIMG,
    const float* __restrict__ R, float* __restrict__ out)
{
    __shared__ char lds[81920];

    const int t    = threadIdx.x;
    const int lane = t & 63, wid = t >> 6;
    const int bn = blockIdx.y, q0 = blockIdx.x * 128;
    const int b  = bn >> 3,  n = bn & 7;
    const int l31 = lane & 31, h5 = lane >> 5;
    const int q_local = wid * 32 + l31;
    const int q = q0 + q_local;

    short8 qh[8], ql[8];
    {
        const u16* qrh = Qhi + ((size_t)bn * PP + q) * DH + h5 * 8;
        const u16* qrl = Qlo + ((size_t)bn * PP + q) * DH + h5 * 8;
#pragma unroll
        for (int kk = 0; kk < 8; ++kk) {
            qh[kk] = *(const short8*)(qrh + kk * 16);
            ql[kk] = *(const short8*)(qrl + kk * 16);
        }
    }
    float R2a[16];
    {
        const float* r2p = R + ((size_t)bn * PP + q) * 64 + 32 + h5 * 4;
#pragma unroll
        for (int m_ = 0; m_ < 4; ++m_) {
            float4 v = *(const float4*)(r2p + m_ * 8);
            R2a[m_*4+0] = v.x; R2a[m_*4+1] = v.y; R2a[m_*4+2] = v.z; R2a[m_*4+3] = v.w;
        }
    }
    float* R1p = (float*)(lds + 65536);
    {
#pragma unroll
        for (int r = 0; r < 4; ++r) {
            int idx = t + 256 * r;
            int row = idx >> 3, c4 = (idx & 7) * 4;
            float4 v = *(const float4*)(R + ((size_t)bn * PP + q0 + row) * 64 + c4);
            R1p[row * 32 + ((c4 + 0) ^ (row & 31))] = v.x;
            R1p[row * 32 + ((c4 + 1) ^ (row & 31))] = v.y;
            R1p[row * 32 + ((c4 + 2) ^ (row & 31))] = v.z;
            R1p[row * 32 + ((c4 + 3) ^ (row & 31))] = v.w;
        }
    }

    auto issueK = [&](int kt, int par) {
        const char* src = KIMG + (((size_t)bn * 32 + kt) << 14) + wid * 4096 + lane * 16;
        const char* dst = lds + par * 16384 + wid * 4096;
#pragma unroll
        for (int c = 0; c < 4; ++c)
            __builtin_amdgcn_global_load_lds((GU32*)(src + c * 1024),
                                             (LU32*)(dst + c * 1024), 16, 0, 0);
    };
    auto issueV = [&](int kt) {
        const char* src = VIMG + (((size_t)bn * 32 + kt) << 14) + wid * 4096 + lane * 16;
        const char* dst = lds + 32768 + wid * 4096;
#pragma unroll
        for (int c = 0; c < 4; ++c)
            __builtin_amdgcn_global_load_lds((GU32*)(src + c * 1024),
                                             (LU32*)(dst + c * 1024), 16, 0, 0);
    };

    issueK(0, 0);
    asm volatile("s_waitcnt lgkmcnt(0)" ::: "memory");
    __builtin_amdgcn_s_barrier();
    __builtin_amdgcn_sched_barrier(0);

    f32x16 o_[4];
#pragma unroll
    for (int i = 0; i < 4; ++i)
#pragma unroll
        for (int r = 0; r < 16; ++r) o_[i][r] = 0.f;

    float m_run = -1e30f, l_run = 0.f;
    u32* Pp = (u32*)(lds + 49152 + wid * 4096);

    for (int kt = 0; kt < 32; ++kt) {
        const int par = kt & 1;
        issueV(kt);
        issueK((kt + 1) & 31, par ^ 1);
        asm volatile("s_waitcnt vmcnt(8)" ::: "memory");
        __builtin_amdgcn_sched_barrier(0);
        __builtin_amdgcn_s_barrier();
        __builtin_amdgcn_sched_barrier(0);

        f32x16 s;
#pragma unroll
        for (int r = 0; r < 16; ++r) s[r] = 0.f;
        const char* kb = lds + par * 16384;
#pragma unroll
        for (int kk = 0; kk < 8; ++kk) {
            const int g = kk * 2 + h5;
            const int off = l31 * 256 + ((g ^ (l31 & 15)) << 4);
            short8 kh = *(const short8*)(kb + off);
            short8 kl = *(const short8*)(kb + 8192 + off);
            s = __builtin_amdgcn_mfma_f32_32x32x16_bf16(kh, qh[kk], s, 0, 0, 0);
            s = __builtin_amdgcn_mfma_f32_32x32x16_bf16(kh, ql[kk], s, 0, 0, 0);
            s = __builtin_amdgcn_mfma_f32_32x32x16_bf16(kl, qh[kk], s, 0, 0, 0);
        }
        const float r1 = R1p[q_local * 32 + (kt ^ l31)];

        float mx = -1e30f;
#pragma unroll
        for (int r = 0; r < 16; ++r) {
            s[r] += R2a[r];
            mx = fmaxf(mx, s[r]);
        }
        mx = fmaxf(mx, __shfl_xor(mx, 32));
        const float pmax  = mx + r1;
        const float m_new = fmaxf(m_run, pmax);
        const float alpha = __expf(m_run - m_new);
        const float tsh   = r1 - m_new;
        float rsum = 0.f;
        u32 pw[16];
#pragma unroll
        for (int r = 0; r < 16; ++r) {
            float p = __expf(s[r] + tsh);
            rsum += p;
            u32 ph = f2bf(p);
            u32 pl = f2bf(p - bf2f(ph));
            pw[r] = (ph << 16) | pl;
        }
        rsum += __shfl_xor(rsum, 32);
        l_run = l_run * alpha + rsum;
        m_run = m_new;
#pragma unroll
        for (int r = 0; r < 16; ++r) {
            const int kr = (r & 3) + ((r >> 2) << 3) + h5 * 4;
            Pp[kr * 32 + l31] = pw[r];
        }
#pragma unroll
        for (int i = 0; i < 4; ++i)
#pragma unroll
            for (int r = 0; r < 16; ++r) o_[i][r] *= alpha;

        asm volatile("s_waitcnt vmcnt(4)" ::: "memory");
        __builtin_amdgcn_sched_barrier(0);
        __builtin_amdgcn_s_barrier();
        __builtin_amdgcn_sched_barrier(0);

        const char* vb = lds + 32768;
#pragma unroll
        for (int kk2 = 0; kk2 < 2; ++kk2) {
            u32 pu[8];
            const int kbase = kk2 * 16 + h5 * 8;
#pragma unroll
            for (int j = 0; j < 8; ++j) pu[j] = Pp[(kbase + j) * 32 + l31];
            short8 pH, pL;
#pragma unroll
            for (int j = 0; j < 8; ++j) {
                pH[j] = (short)(pu[j] >> 16);
                pL[j] = (short)(pu[j] & 0xffffu);
            }
#pragma unroll
            for (int nt = 0; nt < 4; ++nt) {
                const int d = nt * 32 + l31;
                const int g = kk2 * 2 + h5;
                const int off = d * 64 + ((g ^ (d & 3)) << 4);
                short8 vh = *(const short8*)(vb + off);
                short8 vl = *(const short8*)(vb + 8192 + off);
                o_[nt] = __builtin_amdgcn_mfma_f32_32x32x16_bf16(vh, pH, o_[nt], 0, 0, 0);
                o_[nt] = __builtin_amdgcn_mfma_f32_32x32x16_bf16(vl, pH, o_[nt], 0, 0, 0);
                o_[nt] = __builtin_amdgcn_mfma_f32_32x32x16_bf16(vh, pL, o_[nt], 0, 0, 0);
            }
        }
        __builtin_amdgcn_s_barrier();
        __builtin_amdgcn_sched_barrier(0);
    }
    asm volatile("s_waitcnt vmcnt(0)" ::: "memory");

    const float inv = 1.f / l_run;
#pragma unroll
    for (int nt = 0; nt < 4; ++nt)
#pragma unroll
        for (int r = 0; r < 16; ++r) {
            const int d = nt * 32 + (r & 3) + ((r >> 2) << 3) + h5 * 4;
            out[((size_t)b * 1024 + n * 128 + d) * PP + q] = o_[nt][r] * inv;
        }
}

// ============================================================================
extern "C" void kernel_launch(void* const* d_in, const int* in_sizes, int n_in,
                              void* d_out, int out_size, void* d_ws, size_t ws_size,
                              hipStream_t stream)
{
    const float* fm   = (const float*)d_in[0];
    const float* wqkv = (const float*)d_in[1];
    const float* relH = (const float*)d_in[2];
    const float* relW = (const float*)d_in[3];
    float* out = (float*)d_out;

    char* ws = (char*)d_ws;
    u16*  Qhi   = (u16*)(ws);
    u16*  Qlo   = (u16*)(ws + (16ull << 20));
    char* KIMG  = ws + (32ull << 20);
    char* VIMG  = ws + (64ull << 20);
    float* R    = (float*)(ws + (96ull << 20));
    char* FIMG  = ws + (96ull << 20);             // overlays R (dead before rel)
    char* AIMG  = ws + (112ull << 20);
    char* RELIMG= ws + (119ull << 20);

    wconv  <<<768, 256, 0, stream>>>(wqkv, AIMG);
    fmconv <<<dim3(16, 8, 8), 256, 0, stream>>>(fm, FIMG);
    relprep<<<8, 256, 0, stream>>>(relH, relW, RELIMG);
    qkv_gemm<<<dim3(8, 24, 8), 256, 0, stream>>>(AIMG, FIMG, Qhi, Qlo, KIMG, VIMG);
    rel_gemm<<<dim3(8, 64), 256, 0, stream>>>(Qhi, Qlo, RELIMG, R);
    attn_kernel<<<dim3(8, 64), 256, 0, stream>>>(Qhi, Qlo, KIMG, VIMG, R, out);
}

// Round 6
// 283.771 us; speedup vs baseline: 6.0710x; 1.0746x over previous
//
#include <hip/hip_runtime.h>

// ---- problem constants ----
#define BATCH 8
#define CIN   512
#define NH    8
#define DH    128
#define PP    1024   // 32*32 positions
#define QK_SCALE 0.08838834764831845f  // 128^-0.5

typedef unsigned int  u32;
typedef unsigned short u16;
typedef __attribute__((ext_vector_type(8)))  short short8;
typedef __attribute__((ext_vector_type(16))) float f32x16;
typedef __attribute__((ext_vector_type(4)))  u32 u32x4;

typedef __attribute__((address_space(1))) const u32 GU32;
typedef __attribute__((address_space(3))) u32 LU32;

// workspace layout (bytes):
//   Qhi    [64][1024][128] u16   @ 0        (16 MB)
//   Qlo    [64][1024][128] u16   @ 16 MB    (16 MB)
//   KIMG   [64*32][16384]  char  @ 32 MB    (32 MB)  per-tile: hi 8KB, lo 8KB
//   VIMG   [64*32][16384]  char  @ 64 MB    (32 MB)
//   R      [64][1024][64]  f32   @ 96 MB    (16 MB)  } overlaid: FIMG dead before
//   FIMG   [8*8*16][16384] char  @ 96 MB    (16 MB)  } rel_gemm writes R
//   AIMG   [24*16][16384]  char  @ 112 MB   (6.3 MB)
//   RELIMG [128 rows]      char  @ 119 MB   (64 KB)  relcat image hi 32K | lo 32K

__device__ inline u32 f2bf(float x) {            // fp32 -> bf16 (RNE)
    u32 u = __float_as_uint(x);
    return (u + 0x7fffu + ((u >> 16) & 1u)) >> 16;
}
__device__ inline float bf2f(u32 h) { return __uint_as_float(h << 16); }

__device__ inline u32 cvtpk(float a, float b) {  // D[15:0]=bf16(a), D[31:16]=bf16(b)
    u32 r; asm("v_cvt_pk_bf16_f32 %0, %1, %2" : "=v"(r) : "v"(a), "v"(b)); return r;
}
// packed hi + exact residual-lo pair for (a,b)
__device__ inline void split2(float a, float b, u32& wh, u32& wl) {
    u32 h = cvtpk(a, b);
    float ha = __uint_as_float(h << 16);
    float hb = __uint_as_float(h & 0xffff0000u);
    wl = cvtpk(a - ha, b - hb);
    wh = h;
}

__device__ inline void cvt8(const float* v, float scl, uint4& hv, uint4& lv) {
    u32 h[8], l[8];
#pragma unroll
    for (int j = 0; j < 8; ++j) {
        float x = v[j] * scl;
        u32 hb = f2bf(x);
        float hf = bf2f(hb);
        u32 lb = f2bf(x - hf);
        h[j] = hb; l[j] = lb;
    }
    hv = make_uint4(h[0] | (h[1] << 16), h[2] | (h[3] << 16),
                    h[4] | (h[5] << 16), h[6] | (h[7] << 16));
    lv = make_uint4(l[0] | (l[1] << 16), l[2] | (l[3] << 16),
                    l[4] | (l[5] << 16), l[6] | (l[7] << 16));
}

// ============================================================================
// Kernel 0a: W -> AIMG (bf16 hi/lo split, Q rows pre-scaled).
// ============================================================================
__global__ __launch_bounds__(256) void wconv(
    const float* __restrict__ w, char* __restrict__ AIMG)
{
    const int gid = blockIdx.x * 256 + threadIdx.x;    // 196608 granules
    const int o  = gid >> 6;
    const int c0 = (gid & 63) << 3;
    const float scl = (o < 1024) ? QK_SCALE : 1.0f;
    float v[8];
    float4 v0 = *(const float4*)(w + (size_t)o * CIN + c0);
    float4 v1 = *(const float4*)(w + (size_t)o * CIN + c0 + 4);
    v[0]=v0.x; v[1]=v0.y; v[2]=v0.z; v[3]=v0.w;
    v[4]=v1.x; v[5]=v1.y; v[6]=v1.z; v[7]=v1.w;
    uint4 hv, lv; cvt8(v, scl, hv, lv);
    const int otile = o >> 7, row = o & 127, chunk = c0 >> 5, g = (c0 >> 3) & 3;
    char* base = AIMG + (size_t)(otile * 16 + chunk) * 16384
               + row * 64 + ((g ^ (row & 3)) << 4);
    *(uint4*)(base)        = hv;
    *(uint4*)(base + 8192) = lv;
}

// ============================================================================
// Kernel 0b: fm -> FIMG (transpose via LDS + bf16 hi/lo split).
// ============================================================================
__global__ __launch_bounds__(256) void fmconv(
    const float* __restrict__ fm, char* __restrict__ FIMG)
{
    __shared__ float Fs[32][128];
    const int t = threadIdx.x;
    const int chunk = blockIdx.x, ptile = blockIdx.y, b = blockIdx.z;
    const float* src = fm + ((size_t)(b * CIN + chunk * 32)) * PP + ptile * 128;
#pragma unroll
    for (int ii = 0; ii < 4; ++ii) {
        int idx = t + 256 * ii;                 // 1024 float4 = 32c x 128p
        int c = idx >> 5, p4 = idx & 31;
        *(float4*)(&Fs[c][p4 * 4]) = *(const float4*)(src + (size_t)c * PP + p4 * 4);
    }
    __syncthreads();
    const int p = t & 127, gb = (t >> 7) * 2;
#pragma unroll
    for (int gi = 0; gi < 2; ++gi) {
        const int g = gb + gi;
        float v[8];
#pragma unroll
        for (int j = 0; j < 8; ++j) v[j] = Fs[g * 8 + j][p];   // 2-way: free
        uint4 hv, lv; cvt8(v, 1.0f, hv, lv);
        char* base = FIMG + (size_t)((b * 8 + ptile) * 16 + chunk) * 16384
                   + p * 64 + ((g ^ (p & 3)) << 4);
        *(uint4*)(base)        = hv;
        *(uint4*)(base + 8192) = lv;
    }
}

// ============================================================================
// Kernel 0c: relH/relW -> RELIMG (relcat image, 128 rows x 128 d, split bf16).
// ============================================================================
__global__ __launch_bounds__(256) void relprep(
    const float* __restrict__ relH, const float* __restrict__ relW,
    char* __restrict__ RELIMG)
{
    const int idx = blockIdx.x * 256 + threadIdx.x;   // 2048 granules
    const int r = idx >> 4, g = idx & 15;
    float v[8];
    if (r < 63) {
        float4 v0 = *(const float4*)(relH + (size_t)r * DH + g * 8);
        float4 v1 = *(const float4*)(relH + (size_t)r * DH + g * 8 + 4);
        v[0]=v0.x; v[1]=v0.y; v[2]=v0.z; v[3]=v0.w;
        v[4]=v1.x; v[5]=v1.y; v[6]=v1.z; v[7]=v1.w;
    } else if (r < 126) {
        float4 v0 = *(const float4*)(relW + (size_t)(r - 63) * DH + g * 8);
        float4 v1 = *(const float4*)(relW + (size_t)(r - 63) * DH + g * 8 + 4);
        v[0]=v0.x; v[1]=v0.y; v[2]=v0.z; v[3]=v0.w;
        v[4]=v1.x; v[5]=v1.y; v[6]=v1.z; v[7]=v1.w;
    } else {
#pragma unroll
        for (int j = 0; j < 8; ++j) v[j] = 0.f;
    }
    uint4 hv, lv; cvt8(v, 1.0f, hv, lv);
    char* base = RELIMG + r * 256 + ((g ^ (r & 15)) << 4);
    *(uint4*)(base)         = hv;
    *(uint4*)(base + 32768) = lv;
}

// ============================================================================
// Kernel 1: QKV projection as split-bf16 MFMA GEMM (unchanged).
// ============================================================================
__global__ __launch_bounds__(256, 2) void qkv_gemm(
    const char* __restrict__ AIMG, const char* __restrict__ FIMG,
    u16* __restrict__ Qhi, u16* __restrict__ Qlo,
    char* __restrict__ KIMG, char* __restrict__ VIMG)
{
    __shared__ char lds[65536];       // 2 x (A 16KB | B 16KB); reused as Cs

    const int t = threadIdx.x, lane = t & 63, wid = t >> 6;
    const int l31 = lane & 31, h5 = lane >> 5;
    const int ptile = blockIdx.x, otile = blockIdx.y, b = blockIdx.z;
    const int wr = wid >> 1, wc = wid & 1;

    const char* Achunks = AIMG + (size_t)(otile * 16) * 16384;
    const char* Bchunks = FIMG + (size_t)((b * 8 + ptile) * 16) * 16384;

    const int half = wid & 1;
    const char* srcTile = (wid < 2) ? Achunks : Bchunks;
    char* dstBase0 = lds + ((wid < 2) ? 0 : 16384) + half * 8192;   // wave-uniform

    auto stageChunk = [&](int chunk, int par) {
        const char* src = srcTile + (size_t)chunk * 16384 + half * 8192 + lane * 16;
        char* dst = dstBase0 + par * 32768;
#pragma unroll
        for (int c = 0; c < 8; ++c)
            __builtin_amdgcn_global_load_lds((GU32*)(src + c * 1024),
                                             (LU32*)(dst + c * 1024), 16, 0, 0);
    };

    f32x16 acc[2][2];
#pragma unroll
    for (int i = 0; i < 2; ++i)
#pragma unroll
        for (int j = 0; j < 2; ++j)
#pragma unroll
            for (int r = 0; r < 16; ++r) acc[i][j][r] = 0.f;

    auto computeChunk = [&](int par) {
        const char* Abuf = lds + par * 32768;
        const char* Bbuf = Abuf + 16384;
#pragma unroll
        for (int ks = 0; ks < 2; ++ks) {
            short8 a_h[2], a_l[2], b_h[2], b_l[2];
#pragma unroll
            for (int ot = 0; ot < 2; ++ot) {
                const int row = wr * 64 + ot * 32 + l31;
                const int off = row * 64 + (((ks * 2 + h5) ^ (row & 3)) << 4);
                a_h[ot] = *(const short8*)(Abuf + off);
                a_l[ot] = *(const short8*)(Abuf + 8192 + off);
            }
#pragma unroll
            for (int pt = 0; pt < 2; ++pt) {
                const int col = wc * 64 + pt * 32 + l31;
                const int off = col * 64 + (((ks * 2 + h5) ^ (col & 3)) << 4);
                b_h[pt] = *(const short8*)(Bbuf + off);
                b_l[pt] = *(const short8*)(Bbuf + 8192 + off);
            }
#pragma unroll
            for (int ot = 0; ot < 2; ++ot)
#pragma unroll
                for (int pt = 0; pt < 2; ++pt) {
                    acc[ot][pt] = __builtin_amdgcn_mfma_f32_32x32x16_bf16(a_h[ot], b_h[pt], acc[ot][pt], 0, 0, 0);
                    acc[ot][pt] = __builtin_amdgcn_mfma_f32_32x32x16_bf16(a_h[ot], b_l[pt], acc[ot][pt], 0, 0, 0);
                    acc[ot][pt] = __builtin_amdgcn_mfma_f32_32x32x16_bf16(a_l[ot], b_h[pt], acc[ot][pt], 0, 0, 0);
                }
        }
    };

    stageChunk(0, 0);
    for (int ch = 0; ch < 15; ++ch) {
        stageChunk(ch + 1, (ch + 1) & 1);
        asm volatile("s_waitcnt vmcnt(8)" ::: "memory");
        __builtin_amdgcn_sched_barrier(0);
        __builtin_amdgcn_s_barrier();
        __builtin_amdgcn_sched_barrier(0);
        computeChunk(ch & 1);
        __builtin_amdgcn_s_barrier();
        __builtin_amdgcn_sched_barrier(0);
    }
    asm volatile("s_waitcnt vmcnt(0)" ::: "memory");
    __builtin_amdgcn_sched_barrier(0);
    __builtin_amdgcn_s_barrier();
    __builtin_amdgcn_sched_barrier(0);
    computeChunk(1);                  // chunk 15
    __syncthreads();                  // all frag reads done; LDS -> Cs

    // ---- restage C tile (fp32, XOR-swizzled): Cs[o*128 + (p ^ (o&31))]
    float* Cs = (float*)lds;
#pragma unroll
    for (int ot = 0; ot < 2; ++ot)
#pragma unroll
        for (int pt = 0; pt < 2; ++pt)
#pragma unroll
            for (int r = 0; r < 16; ++r) {
                const int o = wr * 64 + ot * 32 + (r & 3) + 8 * (r >> 2) + 4 * h5;
                const int p = wc * 64 + pt * 32 + l31;
                Cs[o * 128 + (p ^ (o & 31))] = acc[ot][pt][r];
            }
    __syncthreads();

    const int tsel = otile >> 3;      // 0=Q 1=K 2=V
    const int n    = otile & 7;
    const int bn   = b * NH + n;

    if (tsel == 0) {
        const int d0 = (t & 15) * 8, prow = t >> 4;
#pragma unroll
        for (int i = 0; i < 8; ++i) {
            const int p = prow + 16 * i;
            float v[8];
#pragma unroll
            for (int j = 0; j < 8; ++j)
                v[j] = Cs[(d0 + j) * 128 + (p ^ ((d0 + j) & 31))];
            uint4 hv, lv; cvt8(v, 1.0f, hv, lv);
            const size_t off = ((size_t)bn * PP + ptile * 128 + p) * DH + d0;
            *(uint4*)(Qhi + off) = hv;
            *(uint4*)(Qlo + off) = lv;
        }
    } else if (tsel == 1) {
        const int d0 = (t & 15) * 8, prow = t >> 4;
#pragma unroll
        for (int i = 0; i < 8; ++i) {
            const int p = prow + 16 * i;
            float v[8];
#pragma unroll
            for (int j = 0; j < 8; ++j)
                v[j] = Cs[(d0 + j) * 128 + (p ^ ((d0 + j) & 31))];
            uint4 hv, lv; cvt8(v, 1.0f, hv, lv);
            const int kt = ptile * 4 + (p >> 5), r32 = p & 31;
            char* base = KIMG + ((size_t)(bn * 32 + kt) << 14)
                       + r32 * 256 + (((d0 >> 3) ^ (r32 & 15)) << 4);
            *(uint4*)(base)        = hv;
            *(uint4*)(base + 8192) = lv;
        }
    } else {
        const int g = t & 3, dbase = t >> 2;
#pragma unroll
        for (int i = 0; i < 2; ++i) {
            const int d = dbase + 64 * i;
#pragma unroll
            for (int ks = 0; ks < 4; ++ks) {
                const int p0 = ks * 32 + g * 8;
                float v[8];
#pragma unroll
                for (int j = 0; j < 8; ++j)
                    v[j] = Cs[d * 128 + ((p0 + j) ^ (d & 31))];
                uint4 hv, lv; cvt8(v, 1.0f, hv, lv);
                char* base = VIMG + ((size_t)(bn * 32 + ptile * 4 + ks) << 14)
                           + d * 64 + ((g ^ (d & 3)) << 4);
                *(uint4*)(base)        = hv;
                *(uint4*)(base + 8192) = lv;
            }
        }
    }
}

// ============================================================================
// Kernel 2: rel logits as split-bf16 MFMA GEMM + in-LDS window scatter.
// (unchanged)
// ============================================================================
__global__ __launch_bounds__(256, 1) void rel_gemm(
    const u16* __restrict__ Qhi, const u16* __restrict__ Qlo,
    const char* __restrict__ RELIMG, float* __restrict__ R)
{
    __shared__ char lds[131072];
    const int t = threadIdx.x, lane = t & 63, wid = t >> 6;
    const int l31 = lane & 31, h5 = lane >> 5;
    const int bn = blockIdx.y, p0 = blockIdx.x * 128;

    {
        const char* src = RELIMG + wid * 16384 + lane * 16;
        char* dst = lds + wid * 16384;
#pragma unroll
        for (int c = 0; c < 16; ++c)
            __builtin_amdgcn_global_load_lds((GU32*)(src + c * 1024),
                                             (LU32*)(dst + c * 1024), 16, 0, 0);
    }
#pragma unroll
    for (int pt = 0; pt < 4; ++pt) {
#pragma unroll
        for (int half = 0; half < 2; ++half) {
            const u16* srcp = (half ? Qlo : Qhi) + ((size_t)bn * PP + p0 + pt * 32) * DH;
            char* dstb = lds + 65536 + pt * 16384 + half * 8192;
#pragma unroll
            for (int ii = 0; ii < 2; ++ii) {
                const int f = t + 256 * ii;              // granule 0..511
                const int p = f >> 4, g = f & 15;
                uint4 v = *(const uint4*)((const char*)srcp + f * 16);
                *(uint4*)(dstb + p * 256 + ((g ^ (p & 15)) << 4)) = v;
            }
        }
    }
    asm volatile("s_waitcnt vmcnt(0) lgkmcnt(0)" ::: "memory");
    __builtin_amdgcn_s_barrier();
    __builtin_amdgcn_sched_barrier(0);

    f32x16 acc[4];
#pragma unroll
    for (int i = 0; i < 4; ++i)
#pragma unroll
        for (int r = 0; r < 16; ++r) acc[i][r] = 0.f;

    const int rrow = wid * 32 + l31;
#pragma unroll
    for (int kk = 0; kk < 8; ++kk) {
        const int g = kk * 2 + h5;
        const int aoff = rrow * 256 + ((g ^ (rrow & 15)) << 4);
        short8 ah = *(const short8*)(lds + aoff);
        short8 al = *(const short8*)(lds + 32768 + aoff);
        const int boff = l31 * 256 + ((g ^ (l31 & 15)) << 4);
#pragma unroll
        for (int pt = 0; pt < 4; ++pt) {
            const char* bb = lds + 65536 + pt * 16384;
            short8 bh = *(const short8*)(bb + boff);
            short8 bl = *(const short8*)(bb + 8192 + boff);
            acc[pt] = __builtin_amdgcn_mfma_f32_32x32x16_bf16(ah, bh, acc[pt], 0, 0, 0);
            acc[pt] = __builtin_amdgcn_mfma_f32_32x32x16_bf16(ah, bl, acc[pt], 0, 0, 0);
            acc[pt] = __builtin_amdgcn_mfma_f32_32x32x16_bf16(al, bh, acc[pt], 0, 0, 0);
        }
    }
    __syncthreads();                  // all LDS reads done -> overlay Cs

    float* Cs = (float*)lds;          // [128 j'][132] padded
#pragma unroll
    for (int pt = 0; pt < 4; ++pt)
#pragma unroll
        for (int r = 0; r < 16; ++r) {
            const int jr = wid * 32 + (r & 3) + 8 * (r >> 2) + 4 * h5;
            Cs[jr * 132 + pt * 32 + l31] = acc[pt][r];
        }
    __syncthreads();

    const int pl = t >> 1, jh = t & 1;
    const int pg = p0 + pl, hq = pg >> 5, wq = pg & 31;
    const int base = jh ? (94 - wq) : (31 - hq);
    float* dst = R + ((size_t)bn * PP + pg) * 64 + jh * 32;
#pragma unroll
    for (int j4 = 0; j4 < 8; ++j4) {
        float4 v;
        v.x = Cs[(base + j4 * 4 + 0) * 132 + pl];
        v.y = Cs[(base + j4 * 4 + 1) * 132 + pl];
        v.z = Cs[(base + j4 * 4 + 2) * 132 + pl];
        v.w = Cs[(base + j4 * 4 + 3) * 132 + pl];
        *(float4*)(dst + j4 * 4) = v;
    }
}

// ============================================================================
// Kernel 3: split-bf16 MFMA flash attention.
// Round-6 changes: P kept in-register (cvt_pk + permlane32_swap, no P LDS),
// defer-max rescale (THR=8), setprio around MFMA clusters, XCD-aware block
// swizzle (all 8 q-tiles of a bn on one XCD), LDS 80K -> 64K.
// LDS: Kbuf0 16K | Kbuf1 16K | Vbuf 16K | R1 16K
// ============================================================================
__global__ __launch_bounds__(256, 2) void attn_kernel(
    const u16* __restrict__ Qhi, const u16* __restrict__ Qlo,
    const char* __restrict__ KIMG, const char* __restrict__ VIMG,
    const float* __restrict__ R, float* __restrict__ out)
{
    __shared__ char lds[65536];

    const int t    = threadIdx.x;
    const int lane = t & 63, wid = t >> 6;
    // XCD swizzle: lin = c*64 + m*8 + r  ->  bn = r*8+c (XCD r), q-tile = m
    const int lin = blockIdx.x;
    const int bn  = (lin & 7) * 8 + (lin >> 6);
    const int q0  = ((lin >> 3) & 7) * 128;
    const int b  = bn >> 3,  n = bn & 7;
    const int l31 = lane & 31, h5 = lane >> 5;
    const int q_local = wid * 32 + l31;
    const int q = q0 + q_local;

    short8 qh[8], ql[8];
    {
        const u16* qrh = Qhi + ((size_t)bn * PP + q) * DH + h5 * 8;
        const u16* qrl = Qlo + ((size_t)bn * PP + q) * DH + h5 * 8;
#pragma unroll
        for (int kk = 0; kk < 8; ++kk) {
            qh[kk] = *(const short8*)(qrh + kk * 16);
            ql[kk] = *(const short8*)(qrl + kk * 16);
        }
    }
    float R2a[16];
    {
        const float* r2p = R + ((size_t)bn * PP + q) * 64 + 32 + h5 * 4;
#pragma unroll
        for (int m_ = 0; m_ < 4; ++m_) {
            float4 v = *(const float4*)(r2p + m_ * 8);
            R2a[m_*4+0] = v.x; R2a[m_*4+1] = v.y; R2a[m_*4+2] = v.z; R2a[m_*4+3] = v.w;
        }
    }
    float* R1p = (float*)(lds + 49152);
    {
#pragma unroll
        for (int r = 0; r < 4; ++r) {
            int idx = t + 256 * r;
            int row = idx >> 3, c4 = (idx & 7) * 4;
            float4 v = *(const float4*)(R + ((size_t)bn * PP + q0 + row) * 64 + c4);
            R1p[row * 32 + ((c4 + 0) ^ (row & 31))] = v.x;
            R1p[row * 32 + ((c4 + 1) ^ (row & 31))] = v.y;
            R1p[row * 32 + ((c4 + 2) ^ (row & 31))] = v.z;
            R1p[row * 32 + ((c4 + 3) ^ (row & 31))] = v.w;
        }
    }

    auto issueK = [&](int kt, int par) {
        const char* src = KIMG + (((size_t)bn * 32 + kt) << 14) + wid * 4096 + lane * 16;
        const char* dst = lds + par * 16384 + wid * 4096;
#pragma unroll
        for (int c = 0; c < 4; ++c)
            __builtin_amdgcn_global_load_lds((GU32*)(src + c * 1024),
                                             (LU32*)(dst + c * 1024), 16, 0, 0);
    };
    auto issueV = [&](int kt) {
        const char* src = VIMG + (((size_t)bn * 32 + kt) << 14) + wid * 4096 + lane * 16;
        const char* dst = lds + 32768 + wid * 4096;
#pragma unroll
        for (int c = 0; c < 4; ++c)
            __builtin_amdgcn_global_load_lds((GU32*)(src + c * 1024),
                                             (LU32*)(dst + c * 1024), 16, 0, 0);
    };

    issueK(0, 0);
    asm volatile("s_waitcnt lgkmcnt(0)" ::: "memory");   // R1 writes done
    __builtin_amdgcn_s_barrier();
    __builtin_amdgcn_sched_barrier(0);

    f32x16 o_[4];
#pragma unroll
    for (int i = 0; i < 4; ++i)
#pragma unroll
        for (int r = 0; r < 16; ++r) o_[i][r] = 0.f;

    float m_run = -1e30f, l_run = 0.f;

    for (int kt = 0; kt < 32; ++kt) {
        const int par = kt & 1;
        issueV(kt);
        issueK((kt + 1) & 31, par ^ 1);
        asm volatile("s_waitcnt vmcnt(8)" ::: "memory");   // K(t) landed
        __builtin_amdgcn_sched_barrier(0);
        __builtin_amdgcn_s_barrier();
        __builtin_amdgcn_sched_barrier(0);

        // ---- QK^T (swapped): S^T[key][q]
        f32x16 s;
#pragma unroll
        for (int r = 0; r < 16; ++r) s[r] = 0.f;
        const char* kb = lds + par * 16384;
        __builtin_amdgcn_s_setprio(1);
#pragma unroll
        for (int kk = 0; kk < 8; ++kk) {
            const int g = kk * 2 + h5;
            const int off = l31 * 256 + ((g ^ (l31 & 15)) << 4);
            short8 kh = *(const short8*)(kb + off);
            short8 kl = *(const short8*)(kb + 8192 + off);
            s = __builtin_amdgcn_mfma_f32_32x32x16_bf16(kh, qh[kk], s, 0, 0, 0);
            s = __builtin_amdgcn_mfma_f32_32x32x16_bf16(kh, ql[kk], s, 0, 0, 0);
            s = __builtin_amdgcn_mfma_f32_32x32x16_bf16(kl, qh[kk], s, 0, 0, 0);
        }
        __builtin_amdgcn_s_setprio(0);
        const float r1 = R1p[q_local * 32 + (kt ^ l31)];

        // ---- online softmax (q lane-local), defer-max rescale
        float mx = -1e30f;
#pragma unroll
        for (int r = 0; r < 16; ++r) {
            s[r] += R2a[r];
            mx = fmaxf(mx, s[r]);
        }
        mx = fmaxf(mx, __shfl_xor(mx, 32));
        const float pmax = mx + r1;
        if (__any(pmax > m_run + 8.0f)) {
            const float m_new = fmaxf(m_run, pmax);
            const float alpha = __expf(m_run - m_new);
            l_run *= alpha;
#pragma unroll
            for (int i = 0; i < 4; ++i)
#pragma unroll
                for (int r = 0; r < 16; ++r) o_[i][r] *= alpha;
            m_run = m_new;
        }
        const float tsh = r1 - m_run;
        float pf[16];
        float rsum = 0.f;
#pragma unroll
        for (int r = 0; r < 16; ++r) {
            float p = __expf(s[r] + tsh);
            rsum += p;
            pf[r] = p;
        }
        rsum += __shfl_xor(rsum, 32);
        l_run += rsum;

        // ---- build PV B-fragments in-register (cvt_pk + permlane32_swap)
        // S rows at lane (q=l31,h5): k(r) = (r&3) + 8*(r>>2) + 4*h5.
        // For kk2, frag word m must hold keys kk2*16 + h5*8 + {2m, 2m+1}.
        short8 pH[2], pL[2];
#pragma unroll
        for (int kk2 = 0; kk2 < 2; ++kk2) {
            const int b8 = kk2 * 8;
            u32 h0, l0, h1, l1, h2, l2, h3, l3;
            split2(pf[b8 + 0], pf[b8 + 1], h0, l0);
            split2(pf[b8 + 2], pf[b8 + 3], h1, l1);
            split2(pf[b8 + 4], pf[b8 + 5], h2, l2);
            split2(pf[b8 + 6], pf[b8 + 7], h3, l3);
            asm("v_permlane32_swap_b32 %0, %1" : "+v"(h0), "+v"(h2));
            asm("v_permlane32_swap_b32 %0, %1" : "+v"(h1), "+v"(h3));
            asm("v_permlane32_swap_b32 %0, %1" : "+v"(l0), "+v"(l2));
            asm("v_permlane32_swap_b32 %0, %1" : "+v"(l1), "+v"(l3));
            u32x4 vh = {h0, h1, h2, h3};
            u32x4 vl = {l0, l1, l2, l3};
            pH[kk2] = __builtin_bit_cast(short8, vh);
            pL[kk2] = __builtin_bit_cast(short8, vl);
        }

        asm volatile("s_waitcnt vmcnt(4)" ::: "memory");   // V(t) landed
        __builtin_amdgcn_sched_barrier(0);
        __builtin_amdgcn_s_barrier();
        __builtin_amdgcn_sched_barrier(0);

        // ---- PV: O^T[d][q] += Vt * P^T
        const char* vb = lds + 32768;
        __builtin_amdgcn_s_setprio(1);
#pragma unroll
        for (int kk2 = 0; kk2 < 2; ++kk2) {
#pragma unroll
            for (int nt = 0; nt < 4; ++nt) {
                const int d = nt * 32 + l31;
                const int g = kk2 * 2 + h5;
                const int off = d * 64 + ((g ^ (d & 3)) << 4);
                short8 vh = *(const short8*)(vb + off);
                short8 vl = *(const short8*)(vb + 8192 + off);
                o_[nt] = __builtin_amdgcn_mfma_f32_32x32x16_bf16(vh, pH[kk2], o_[nt], 0, 0, 0);
                o_[nt] = __builtin_amdgcn_mfma_f32_32x32x16_bf16(vl, pH[kk2], o_[nt], 0, 0, 0);
                o_[nt] = __builtin_amdgcn_mfma_f32_32x32x16_bf16(vh, pL[kk2], o_[nt], 0, 0, 0);
            }
        }
        __builtin_amdgcn_s_setprio(0);
        __builtin_amdgcn_s_barrier();     // K(t)/V(t) buffers free
        __builtin_amdgcn_sched_barrier(0);
    }
    asm volatile("s_waitcnt vmcnt(0)" ::: "memory");

    const float inv = 1.f / l_run;
#pragma unroll
    for (int nt = 0; nt < 4; ++nt)
#pragma unroll
        for (int r = 0; r < 16; ++r) {
            const int d = nt * 32 + (r & 3) + ((r >> 2) << 3) + h5 * 4;
            out[((size_t)b * 1024 + n * 128 + d) * PP + q] = o_[nt][r] * inv;
        }
}

// ============================================================================
extern "C" void kernel_launch(void* const* d_in, const int* in_sizes, int n_in,
                              void* d_out, int out_size, void* d_ws, size_t ws_size,
                              hipStream_t stream)
{
    const float* fm   = (const float*)d_in[0];
    const float* wqkv = (const float*)d_in[1];
    const float* relH = (const float*)d_in[2];
    const float* relW = (const float*)d_in[3];
    float* out = (float*)d_out;

    char* ws = (char*)d_ws;
    u16*  Qhi   = (u16*)(ws);
    u16*  Qlo   = (u16*)(ws + (16ull << 20));
    char* KIMG  = ws + (32ull << 20);
    char* VIMG  = ws + (64ull << 20);
    float* R    = (float*)(ws + (96ull << 20));
    char* FIMG  = ws + (96ull << 20);             // overlays R (dead before rel)
    char* AIMG  = ws + (112ull << 20);
    char* RELIMG= ws + (119ull << 20);

    wconv  <<<768, 256, 0, stream>>>(wqkv, AIMG);
    fmconv <<<dim3(16, 8, 8), 256, 0, stream>>>(fm, FIMG);
    relprep<<<8, 256, 0, stream>>>(relH, relW, RELIMG);
    qkv_gemm<<<dim3(8, 24, 8), 256, 0, stream>>>(AIMG, FIMG, Qhi, Qlo, KIMG, VIMG);
    rel_gemm<<<dim3(8, 64), 256, 0, stream>>>(Qhi, Qlo, RELIMG, R);
    attn_kernel<<<512, 256, 0, stream>>>(Qhi, Qlo, KIMG, VIMG, R, out);
}